// Round 1
// baseline (4994.195 us; speedup 1.0000x reference)
//
#include <hip/hip_runtime.h>
#include <math.h>

// ---------------------------------------------------------------------------
// GraphConvNetLSTM: GCN (3 layers, reassociated Ahat@(H@W.T)) + 3-layer
// bidirectional LSTM encode over 4096 nodes + 4096-step autoregressive decode.
// Output: sigmoid(dec_outs @ Wo + bo), 4096 floats.
// ---------------------------------------------------------------------------

#define HID 5
#define GCN 10

__device__ __forceinline__ float rl(float v, int l) {
    // wave-uniform lane broadcast (v_readlane -> SGPR)
    return __int_as_float(__builtin_amdgcn_readlane(__float_as_int(v), l));
}
__device__ __forceinline__ float frcp(float x) { return __builtin_amdgcn_rcpf(x); }

__device__ __forceinline__ float selu_f(float x) {
    const float lam = 1.0507009873554805f;
    const float la  = 1.7580993408473766f;   // lam * alpha
    return x > 0.f ? lam * x : la * (__expf(x) - 1.f);
}

// ---- deg -> s = 1/sqrt(rowsum(A)) -----------------------------------------
__global__ __launch_bounds__(256) void k_rowsum(const float* __restrict__ A,
                                                float* __restrict__ s, int n) {
    __shared__ float red[256];
    const int i   = blockIdx.x;
    const int tid = threadIdx.x;
    const float4* row4 = (const float4*)(A + (size_t)i * n);
    float acc = 0.f;
    for (int j = tid; j < n / 4; j += 256) {
        float4 a = row4[j];
        acc += (a.x + a.y) + (a.z + a.w);
    }
    red[tid] = acc; __syncthreads();
    #pragma unroll
    for (int w = 128; w > 0; w >>= 1) {
        if (tid < w) red[tid] += red[tid + w];
        __syncthreads();
    }
    if (tid == 0) {
        float deg = red[0];
        s[i] = (deg > 0.f) ? rsqrtf(deg) : 0.f;
    }
}

// ---- Ys[i,:] = s_i * (Hin[i,:] @ W.T)   (W is (10, fin), torch layout) ----
__global__ __launch_bounds__(256) void k_xw(const float* __restrict__ Hin,
                                            const float* __restrict__ W,
                                            const float* __restrict__ s,
                                            float* __restrict__ Ys,
                                            int n, int fin) {
    const int i   = blockIdx.x;
    const int tid = threadIdx.x;
    float acc[GCN];
    #pragma unroll
    for (int o = 0; o < GCN; ++o) acc[o] = 0.f;
    const float* hr = Hin + (size_t)i * fin;
    for (int j = tid; j < fin; j += 256) {
        float hv = hr[j];
        #pragma unroll
        for (int o = 0; o < GCN; ++o) acc[o] = fmaf(hv, W[o * fin + j], acc[o]);
    }
    // wave-level butterfly reduce, then combine 4 waves via LDS
    #pragma unroll
    for (int o = 0; o < GCN; ++o) {
        float v = acc[o];
        #pragma unroll
        for (int off = 32; off > 0; off >>= 1) v += __shfl_xor(v, off);
        acc[o] = v;
    }
    __shared__ float part[4][GCN];
    const int wv = tid >> 6, ln = tid & 63;
    if (ln == 0) {
        #pragma unroll
        for (int o = 0; o < GCN; ++o) part[wv][o] = acc[o];
    }
    __syncthreads();
    if (tid < GCN) {
        float dot = part[0][tid] + part[1][tid] + part[2][tid] + part[3][tid];
        Ys[i * GCN + tid] = s[i] * dot;
    }
}

// ---- Hout[i,:] = selu( s_i * (A[i,:] @ Ys + Ys[i,:]) ) --------------------
__global__ __launch_bounds__(256) void k_apass(const float* __restrict__ A,
                                               const float* __restrict__ s,
                                               const float* __restrict__ Ys,
                                               float* __restrict__ Hout, int n) {
    const int i   = blockIdx.x;
    const int tid = threadIdx.x;
    float acc[GCN];
    #pragma unroll
    for (int o = 0; o < GCN; ++o) acc[o] = 0.f;
    const float4* row4 = (const float4*)(A + (size_t)i * n);
    for (int j4 = tid; j4 < n / 4; j4 += 256) {
        float4 a = row4[j4];
        const float* y0 = Ys + (size_t)(4 * j4) * GCN;
        #pragma unroll
        for (int o = 0; o < GCN; ++o) {
            acc[o] = fmaf(a.x, y0[o],          acc[o]);
            acc[o] = fmaf(a.y, y0[GCN + o],    acc[o]);
            acc[o] = fmaf(a.z, y0[2*GCN + o],  acc[o]);
            acc[o] = fmaf(a.w, y0[3*GCN + o],  acc[o]);
        }
    }
    #pragma unroll
    for (int o = 0; o < GCN; ++o) {
        float v = acc[o];
        #pragma unroll
        for (int off = 32; off > 0; off >>= 1) v += __shfl_xor(v, off);
        acc[o] = v;
    }
    __shared__ float part[4][GCN];
    const int wv = tid >> 6, ln = tid & 63;
    if (ln == 0) {
        #pragma unroll
        for (int o = 0; o < GCN; ++o) part[wv][o] = acc[o];
    }
    __syncthreads();
    if (tid < GCN) {
        float dot = part[0][tid] + part[1][tid] + part[2][tid] + part[3][tid];
        float z = s[i] * (dot + Ys[i * GCN + tid]);
        Hout[i * GCN + tid] = selu_f(z);
    }
}

// ---- single-wave sequential LSTM encode + autoregressive decode -----------
// Lane layout (one wave = 64 lanes):
//   lanes 0..39 : gate lanes. d = lane/20 (direction), g = lane%20 (gate row,
//                 0-4=i, 5-9=f, 10-14=g, 15-19=o). Per-layer weight row in regs.
//   lanes 0..9  : additionally hold state h/c for (d = lane/5, u = lane%5) --
//                 this matches the reference concat order [dir0(5), dir1(5)].
__global__ __launch_bounds__(64, 1) void k_lstm(
    const float* __restrict__ H,     // (n,10) encode inputs
    const float* __restrict__ W_ih,  // (6,20,10)
    const float* __restrict__ W_hh,  // (6,20,5)
    const float* __restrict__ b_ih,  // (6,20)
    const float* __restrict__ b_hh,  // (6,20)
    const float* __restrict__ h0,    // (6,5)
    const float* __restrict__ c0,    // (6,5)
    const float* __restrict__ tok,   // (10)
    const float* __restrict__ Wo,    // (10)
    const float* __restrict__ bo,    // (1)
    float* __restrict__ out, int n)
{
    const int  lane = threadIdx.x;
    const bool gl   = lane < 40;
    const int  d    = gl ? (lane / 20) : 0;
    const int  g    = lane % 20;
    const int  gt   = g / 5;                    // 0=i,1=f,2=g,3=o
    const bool isg  = (gt == 2);
    const float esc = isg ? -2.f : -1.f;        // sigmoid: exp(-x); tanh: exp(-2x)
    const int  base = (lane / 5) * 20 + (lane % 5);  // gather src for lanes 0..9

    // per-layer weights into registers; whh widened to 10 with zeros for the
    // other direction so the h-broadcast loop is uniform.
    float wih[3][10], whh[3][10], bias[3];
    #pragma unroll
    for (int l = 0; l < 3; ++l) {
        const int k = 2 * l + d;
        #pragma unroll
        for (int j = 0; j < 10; ++j)
            wih[l][j] = gl ? W_ih[(k * 20 + g) * 10 + j] : 0.f;
        #pragma unroll
        for (int j = 0; j < 10; ++j)
            whh[l][j] = (gl && (j / 5) == d) ? W_hh[(k * 20 + g) * 5 + (j % 5)] : 0.f;
        bias[l] = gl ? (b_ih[k * 20 + g] + b_hh[k * 20 + g]) : 0.f;
    }
    float h[3], c[3];
    #pragma unroll
    for (int l = 0; l < 3; ++l) {
        if (lane < 10) {
            const int k = 2 * l + lane / 5;
            h[l] = h0[k * 5 + lane % 5];
            c[l] = c0[k * 5 + lane % 5];
        } else { h[l] = 0.f; c[l] = 0.f; }
    }
    float wo[10];
    #pragma unroll
    for (int j = 0; j < 10; ++j) wo[j] = Wo[j];
    const float bo0 = bo[0];

    // one full timestep through the 3-layer bidirectional stack
    auto step = [&](float x) -> float {
        #pragma unroll
        for (int l = 0; l < 3; ++l) {
            // gate pre-activation: 4-way split accumulation to shorten chain
            float a0 = bias[l], a1 = 0.f, a2 = 0.f, a3 = 0.f;
            #pragma unroll
            for (int j = 0; j < 10; j += 2) {
                a0 = fmaf(wih[l][j],     rl(x, j),       a0);
                a1 = fmaf(wih[l][j + 1], rl(x, j + 1),   a1);
            }
            #pragma unroll
            for (int j = 0; j < 10; j += 2) {
                a2 = fmaf(whh[l][j],     rl(h[l], j),     a2);
                a3 = fmaf(whh[l][j + 1], rl(h[l], j + 1), a3);
            }
            float acc = (a0 + a1) + (a2 + a3);
            // unified sigmoid/tanh: e = exp(esc*acc); sig = 1/(1+e); tanh = (1-e)/(1+e)
            float e   = __expf(esc * acc);
            float r   = frcp(1.f + e);
            float act = isg ? (1.f - e) * r : r;
            // gather i/f/g/o for this lane's hidden unit (lanes 0..9 meaningful)
            float iv = __shfl(act, base);
            float fv = __shfl(act, base + 5);
            float gv = __shfl(act, base + 10);
            float ov = __shfl(act, base + 15);
            float cn = fmaf(fv, c[l], iv * gv);
            float e2 = __expf(-2.f * cn);
            float th = (1.f - e2) * frcp(1.f + e2);
            float hn = ov * th;
            if (lane < 10) { h[l] = hn; c[l] = cn; }
            x = hn;   // lanes 0..9 carry next layer's input
        }
        return x;
    };

    // ---- encode: scan H rows; prefetch next row under the step latency ----
    float xv = (lane < 10) ? H[lane] : 0.f;
    #pragma unroll 1
    for (int t = 0; t < n; ++t) {
        float xn = (lane < 10 && (t + 1) < n) ? H[(size_t)(t + 1) * 10 + lane] : 0.f;
        (void)step(xv);
        xv = xn;
    }

    // ---- decode: autoregressive feedback + fused output head --------------
    float dx = (lane < 10) ? tok[lane] : 0.f;
    #pragma unroll 1
    for (int t = 0; t < n; ++t) {
        dx = step(dx);
        float dot = bo0;
        #pragma unroll
        for (int j = 0; j < 10; ++j) dot = fmaf(wo[j], rl(dx, j), dot);
        if (lane == 0) out[t] = frcp(1.f + __expf(-dot));
    }
}

extern "C" void kernel_launch(void* const* d_in, const int* in_sizes, int n_in,
                              void* d_out, int out_size, void* d_ws, size_t ws_size,
                              hipStream_t stream) {
    const float* A    = (const float*)d_in[0];
    const float* X    = (const float*)d_in[1];
    const float* W0   = (const float*)d_in[2];
    const float* W1   = (const float*)d_in[3];
    const float* W2   = (const float*)d_in[4];
    const float* W_ih = (const float*)d_in[5];
    const float* W_hh = (const float*)d_in[6];
    const float* b_ih = (const float*)d_in[7];
    const float* b_hh = (const float*)d_in[8];
    const float* h0   = (const float*)d_in[9];
    const float* c0   = (const float*)d_in[10];
    const float* tok  = (const float*)d_in[11];
    const float* Wo   = (const float*)d_in[12];
    const float* bo   = (const float*)d_in[13];
    float* out = (float*)d_out;

    const int n    = out_size;            // 4096
    const int feat = in_sizes[1] / n;     // 1024

    // workspace: s (n) | b0 (n*10) | b1 (n*10)   -> ~348 KB
    float* s  = (float*)d_ws;
    float* b0 = s + n;
    float* b1 = b0 + (size_t)n * GCN;

    k_rowsum<<<n, 256, 0, stream>>>(A, s, n);
    // layer 0: b0 = s .* (X @ W0.T); b1 = selu(s .* (A@b0 + b0))
    k_xw   <<<n, 256, 0, stream>>>(X,  W0, s, b0, n, feat);
    k_apass<<<n, 256, 0, stream>>>(A, s, b0, b1, n);
    // layer 1
    k_xw   <<<n, 256, 0, stream>>>(b1, W1, s, b0, n, GCN);
    k_apass<<<n, 256, 0, stream>>>(A, s, b0, b1, n);
    // layer 2
    k_xw   <<<n, 256, 0, stream>>>(b1, W2, s, b0, n, GCN);
    k_apass<<<n, 256, 0, stream>>>(A, s, b0, b1, n);
    // sequential encode + autoregressive decode + output head
    k_lstm <<<1, 64, 0, stream>>>(b1, W_ih, W_hh, b_ih, b_hh, h0, c0,
                                  tok, Wo, bo, out, n);
}

// Round 2
// 4234.718 us; speedup vs baseline: 1.1793x; 1.1793x over previous
//
#include <hip/hip_runtime.h>
#include <math.h>

// ---------------------------------------------------------------------------
// GraphConvNetLSTM: GCN (3 layers, reassociated Ahat@(H@W.T), transposed
// 10-wide intermediates) + 3-layer bidir LSTM encode (software-pipelined
// across layers) + 4096-step autoregressive decode. Single-wave LSTM with
// DPP quad-gather (no LDS on the serial chain) and SGPR broadcast reuse.
// ---------------------------------------------------------------------------

#define GCNW 10

__device__ __forceinline__ float rl(float v, int l) {
    return __int_as_float(__builtin_amdgcn_readlane(__float_as_int(v), l));
}
__device__ __forceinline__ float frcp(float x) { return __builtin_amdgcn_rcpf(x); }

#if __has_builtin(__builtin_amdgcn_exp2f)
__device__ __forceinline__ float fexp2(float x) { return __builtin_amdgcn_exp2f(x); }
#else
__device__ __forceinline__ float fexp2(float x) { return __expf(x * 0.6931471805599453f); }
#endif

// quad_perm broadcast: return lane (quad_base + L)'s value to all quad lanes
template <int L>
__device__ __forceinline__ float qb(float v) {
    constexpr int ctrl = L | (L << 2) | (L << 4) | (L << 6);
    int r = __builtin_amdgcn_update_dpp(0, __float_as_int(v), ctrl, 0xF, 0xF, true);
    return __int_as_float(r);
}

__device__ __forceinline__ float selu_f(float x) {
    const float lam = 1.0507009873554805f;
    const float la  = 1.7580993408473766f;   // lam * alpha
    return x > 0.f ? lam * x : la * (__expf(x) - 1.f);
}

// ---- k_pre: blocks [0,n) rowsum->s ; blocks [n,2n) Y0t[o][i] = X[i]@W0.T ---
__global__ __launch_bounds__(256) void k_pre(const float* __restrict__ A,
                                             const float* __restrict__ X,
                                             const float* __restrict__ W0,
                                             float* __restrict__ s,
                                             float* __restrict__ Y0t,
                                             int n, int feat) {
    const int b   = blockIdx.x;
    const int tid = threadIdx.x;
    if (b < n) {
        __shared__ float red[256];
        const float4* row4 = (const float4*)(A + (size_t)b * n);
        float acc = 0.f;
        for (int j = tid; j < n / 4; j += 256) {
            float4 a = row4[j];
            acc += (a.x + a.y) + (a.z + a.w);
        }
        red[tid] = acc; __syncthreads();
        #pragma unroll
        for (int w = 128; w > 0; w >>= 1) {
            if (tid < w) red[tid] += red[tid + w];
            __syncthreads();
        }
        if (tid == 0) {
            float deg = red[0];
            s[b] = (deg > 0.f) ? rsqrtf(deg) : 0.f;
        }
    } else {
        const int i = b - n;
        float acc[GCNW];
        #pragma unroll
        for (int o = 0; o < GCNW; ++o) acc[o] = 0.f;
        const float* xr = X + (size_t)i * feat;
        for (int j = tid; j < feat; j += 256) {
            float xv = xr[j];
            #pragma unroll
            for (int o = 0; o < GCNW; ++o) acc[o] = fmaf(xv, W0[o * feat + j], acc[o]);
        }
        #pragma unroll
        for (int o = 0; o < GCNW; ++o) {
            float v = acc[o];
            #pragma unroll
            for (int off = 32; off > 0; off >>= 1) v += __shfl_xor(v, off);
            acc[o] = v;
        }
        __shared__ float part[4][GCNW];
        const int wv = tid >> 6, ln = tid & 63;
        if (ln == 0) {
            #pragma unroll
            for (int o = 0; o < GCNW; ++o) part[wv][o] = acc[o];
        }
        __syncthreads();
        if (tid < GCNW)
            Y0t[(size_t)tid * n + i] =
                part[0][tid] + part[1][tid] + part[2][tid] + part[3][tid];
    }
}

// ---- k_ap: z = selu(s_i*(sum_j A_ij s_j Y_j + s_i Y_i)); optionally fuse
//      next layer's matvec: Ot[o][i] = z @ W.T (unscaled). Yt is (10, n). ----
__global__ __launch_bounds__(256) void k_ap(const float* __restrict__ A,
                                            const float* __restrict__ s,
                                            const float* __restrict__ Yt,
                                            const float* __restrict__ W,   // (10,10) or null
                                            float* __restrict__ Ot, int n) {
    const int i   = blockIdx.x;
    const int tid = threadIdx.x;
    float acc[GCNW];
    #pragma unroll
    for (int o = 0; o < GCNW; ++o) acc[o] = 0.f;
    const float4* a4 = (const float4*)(A + (size_t)i * n);
    const float4* s4 = (const float4*)s;
    for (int j4 = tid; j4 < n / 4; j4 += 256) {
        float4 a  = a4[j4];
        float4 sv = s4[j4];
        a.x *= sv.x; a.y *= sv.y; a.z *= sv.z; a.w *= sv.w;
        #pragma unroll
        for (int o = 0; o < GCNW; ++o) {
            float4 y = ((const float4*)(Yt + (size_t)o * n))[j4];
            acc[o] = fmaf(a.x, y.x, acc[o]);
            acc[o] = fmaf(a.y, y.y, acc[o]);
            acc[o] = fmaf(a.z, y.z, acc[o]);
            acc[o] = fmaf(a.w, y.w, acc[o]);
        }
    }
    #pragma unroll
    for (int o = 0; o < GCNW; ++o) {
        float v = acc[o];
        #pragma unroll
        for (int off = 32; off > 0; off >>= 1) v += __shfl_xor(v, off);
        acc[o] = v;
    }
    __shared__ float part[4][GCNW];
    __shared__ float zsh[GCNW];
    const int wv = tid >> 6, ln = tid & 63;
    if (ln == 0) {
        #pragma unroll
        for (int o = 0; o < GCNW; ++o) part[wv][o] = acc[o];
    }
    __syncthreads();
    if (tid < GCNW) {
        float dot = part[0][tid] + part[1][tid] + part[2][tid] + part[3][tid];
        float si  = s[i];
        float z   = selu_f(si * (dot + si * Yt[(size_t)tid * n + i]));
        if (W) zsh[tid] = z;
        else   Ot[(size_t)tid * n + i] = z;
    }
    if (W) {
        __syncthreads();
        if (tid < GCNW) {
            float d = 0.f;
            #pragma unroll
            for (int u = 0; u < GCNW; ++u) d = fmaf(zsh[u], W[tid * GCNW + u], d);
            Ot[(size_t)tid * n + i] = d;
        }
    }
}

// ---------------------------------------------------------------------------
// Single-wave LSTM. Lane layout: quad u = lane>>2 (unit slot: d=u/5, unit=u%5,
// matching reference concat [dir0(5), dir1(5)]); gt = lane&3 in {i,f,g,o}.
// Gate value per lane; quad-gather via DPP; hn/c valid on gt==0 lane of each
// quad; cross-stage values travel as SGPR broadcast sets (readlane of lane 4u).
// ---------------------------------------------------------------------------
struct SB { float v[GCNW]; };

__device__ __forceinline__ SB bc(float x) {
    SB r;
    #pragma unroll
    for (int j = 0; j < GCNW; ++j) r.v[j] = rl(x, 4 * j);
    return r;
}

__device__ __forceinline__ float stage(const float (&wi)[GCNW], const float (&wh)[GCNW],
                                       float bias, const SB& x, const SB& h,
                                       float& c, float c2e, bool isg) {
    float a0 = bias, a1 = 0.f, a2 = 0.f, a3 = 0.f;
    #pragma unroll
    for (int j = 0; j < GCNW; j += 2) {
        a0 = fmaf(wi[j],     x.v[j],     a0);
        a1 = fmaf(wi[j + 1], x.v[j + 1], a1);
        a2 = fmaf(wh[j],     h.v[j],     a2);
        a3 = fmaf(wh[j + 1], h.v[j + 1], a3);
    }
    float acc = (a0 + a1) + (a2 + a3);
    // sigmoid(x)=1/(1+2^(-x*log2e)); tanh(x)=(1-e)/(1+e), e=2^(-2x*log2e)
    float e  = fexp2(acc * c2e);
    float r  = frcp(1.f + e);
    float av = isg ? (1.f - e) * r : r;
    // gather f,g,o toward gt==0 lane (it already holds i)
    float fv = qb<1>(av), gv = qb<2>(av), ov = qb<3>(av);
    float cn = fmaf(fv, c, av * gv);       // valid on gt==0 lanes only
    c = cn;
    float e2 = fexp2(cn * -2.8853900817779268f);
    float r2 = frcp(1.f + e2);
    return ov * ((1.f - e2) * r2);         // hn, valid on gt==0 lanes
}

__global__ __launch_bounds__(64, 1) void k_lstm(
    const float* __restrict__ Ht,    // (10, n) encode inputs, transposed
    const float* __restrict__ W_ih,  // (6,20,10)
    const float* __restrict__ W_hh,  // (6,20,5)
    const float* __restrict__ b_ih,  // (6,20)
    const float* __restrict__ b_hh,  // (6,20)
    const float* __restrict__ h0,    // (6,5)
    const float* __restrict__ c0,    // (6,5)
    const float* __restrict__ tok,   // (10)
    const float* __restrict__ Wo,    // (10)
    const float* __restrict__ bo,    // (1)
    float* __restrict__ out, int n)
{
    const int  lane = threadIdx.x;
    const int  ul   = lane >> 2, gt = lane & 3;
    const bool actl = ul < GCNW;               // lanes 0..39
    const int  ulc  = actl ? ul : 0;
    const int  dd   = ulc / 5, un = ulc % 5;
    const int  row  = gt * 5 + un;

    float wih[3][GCNW], whh[3][GCNW], bias[3], hv[3], cs[3];
    #pragma unroll
    for (int l = 0; l < 3; ++l) {
        const int k = 2 * l + dd;
        #pragma unroll
        for (int j = 0; j < GCNW; ++j)
            wih[l][j] = actl ? W_ih[(k * 20 + row) * 10 + j] : 0.f;
        #pragma unroll
        for (int j = 0; j < GCNW; ++j)
            whh[l][j] = (actl && (j / 5) == dd) ? W_hh[(k * 20 + row) * 5 + (j % 5)] : 0.f;
        bias[l] = actl ? (b_ih[k * 20 + row] + b_hh[k * 20 + row]) : 0.f;
        hv[l]   = actl ? h0[k * 5 + un] : 0.f;
        cs[l]   = actl ? c0[k * 5 + un] : 0.f;
    }
    const bool  isg = (gt == 2);
    const float c2e = isg ? -2.8853900817779268f : -1.4426950408889634f;

    SB B0 = bc(hv[0]), B1 = bc(hv[1]), B2 = bc(hv[2]);

    // ---- encode: layers software-pipelined (l0@t, l1@t-1, l2@t-2) ---------
    SB Xc;
    #pragma unroll
    for (int j = 0; j < GCNW; ++j) Xc.v[j] = Ht[(size_t)j * n];
    #pragma unroll 1
    for (int t = 0; t < n + 2; ++t) {
        SB Xn;
        if (t + 1 < n) {
            #pragma unroll
            for (int j = 0; j < GCNW; ++j) Xn.v[j] = Ht[(size_t)j * n + t + 1];
        }
        const bool s0 = t < n, s1 = (t >= 1) & (t < n + 1), s2 = t >= 2;
        float ny0, ny1, ny2;
        if (s0) ny0 = stage(wih[0], whh[0], bias[0], Xc, B0, cs[0], c2e, isg);
        if (s1) ny1 = stage(wih[1], whh[1], bias[1], B0, B1, cs[1], c2e, isg);
        if (s2) ny2 = stage(wih[2], whh[2], bias[2], B1, B2, cs[2], c2e, isg);
        if (s2) B2 = bc(ny2);
        if (s1) B1 = bc(ny1);
        if (s0) B0 = bc(ny0);
        Xc = Xn;
    }

    // ---- decode: autoregressive (strictly chained) + fused output head ----
    float wo[GCNW];
    #pragma unroll
    for (int j = 0; j < GCNW; ++j) wo[j] = Wo[j];
    const float bo0 = bo[0];
    SB X;
    #pragma unroll
    for (int j = 0; j < GCNW; ++j) X.v[j] = tok[j];

    float ob = 0.f;
    #pragma unroll 1
    for (int t = 0; t < n; ++t) {
        float ny0 = stage(wih[0], whh[0], bias[0], X,  B0, cs[0], c2e, isg);
        B0 = bc(ny0);
        float ny1 = stage(wih[1], whh[1], bias[1], B0, B1, cs[1], c2e, isg);
        B1 = bc(ny1);
        float ny2 = stage(wih[2], whh[2], bias[2], B1, B2, cs[2], c2e, isg);
        B2 = bc(ny2);
        float dot = bo0;
        #pragma unroll
        for (int j = 0; j < GCNW; ++j) dot = fmaf(wo[j], B2.v[j], dot);
        float val = frcp(1.f + fexp2(dot * -1.4426950408889634f));
        ob = (lane == (t & 63)) ? val : ob;
        if ((t & 63) == 63) out[t - 63 + lane] = ob;
        X = B2;
    }
    if (n & 63) {               // tail safety (n=4096 -> skipped)
        int base = n & ~63;
        if (base + lane < n) out[base + lane] = ob;
    }
}

extern "C" void kernel_launch(void* const* d_in, const int* in_sizes, int n_in,
                              void* d_out, int out_size, void* d_ws, size_t ws_size,
                              hipStream_t stream) {
    const float* A    = (const float*)d_in[0];
    const float* X    = (const float*)d_in[1];
    const float* W0   = (const float*)d_in[2];
    const float* W1   = (const float*)d_in[3];
    const float* W2   = (const float*)d_in[4];
    const float* W_ih = (const float*)d_in[5];
    const float* W_hh = (const float*)d_in[6];
    const float* b_ih = (const float*)d_in[7];
    const float* b_hh = (const float*)d_in[8];
    const float* h0   = (const float*)d_in[9];
    const float* c0   = (const float*)d_in[10];
    const float* tok  = (const float*)d_in[11];
    const float* Wo   = (const float*)d_in[12];
    const float* bo   = (const float*)d_in[13];
    float* out = (float*)d_out;

    const int n    = out_size;            // 4096
    const int feat = in_sizes[1] / n;     // 1024

    // workspace: s (n) | P0 (10n) | P1 (10n)  -> 21n floats (~344 KB)
    float* s  = (float*)d_ws;
    float* P0 = s + n;
    float* P1 = P0 + (size_t)n * GCNW;

    k_pre<<<2 * n, 256, 0, stream>>>(A, X, W0, s, P0, n, feat);       // s, Y0t
    k_ap <<<n,     256, 0, stream>>>(A, s, P0, W1,      P1, n);       // Y1t
    k_ap <<<n,     256, 0, stream>>>(A, s, P1, W2,      P0, n);       // Y2t
    k_ap <<<n,     256, 0, stream>>>(A, s, P0, nullptr, P1, n);       // Ht
    k_lstm<<<1, 64, 0, stream>>>(P1, W_ih, W_hh, b_ih, b_hh, h0, c0,
                                 tok, Wo, bo, out, n);
}

// Round 3
// 3314.136 us; speedup vs baseline: 1.5069x; 1.2778x over previous
//
#include <hip/hip_runtime.h>
#include <math.h>

// ---------------------------------------------------------------------------
// GraphConvNetLSTM: GCN (3 layers, reassociated Ahat@(H@W.T)) + 3-layer bidir
// LSTM encode (branch-free software-pipelined across layers) + 4096-step
// autoregressive decode (branch-free inner loop). Single-wave LSTM, DPP
// quad-gather, SGPR broadcasts, activation scales folded into weights.
// ---------------------------------------------------------------------------

#define GCNW 10
#define LOG2E 1.4426950408889634f

__device__ __forceinline__ float rl(float v, int l) {
    return __int_as_float(__builtin_amdgcn_readlane(__float_as_int(v), l));
}
__device__ __forceinline__ float frcp(float x) { return __builtin_amdgcn_rcpf(x); }

#if __has_builtin(__builtin_amdgcn_exp2f)
__device__ __forceinline__ float fexp2(float x) { return __builtin_amdgcn_exp2f(x); }
#else
__device__ __forceinline__ float fexp2(float x) { return __expf(x * 0.6931471805599453f); }
#endif

// quad_perm broadcast: lane (quad_base + L) -> all 4 lanes of the quad
template <int L>
__device__ __forceinline__ float qb(float v) {
    constexpr int ctrl = L | (L << 2) | (L << 4) | (L << 6);
    int r = __builtin_amdgcn_update_dpp(0, __float_as_int(v), ctrl, 0xF, 0xF, true);
    return __int_as_float(r);
}

__device__ __forceinline__ float selu_f(float x) {
    const float lam = 1.0507009873554805f;
    const float la  = 1.7580993408473766f;   // lam * alpha
    return x > 0.f ? lam * x : la * (__expf(x) - 1.f);
}

// ---- k_pre: blocks [0,n) rowsum->s ; blocks [n,2n) Y0t[o][i] = X[i]@W0.T ---
__global__ __launch_bounds__(256) void k_pre(const float* __restrict__ A,
                                             const float* __restrict__ X,
                                             const float* __restrict__ W0,
                                             float* __restrict__ s,
                                             float* __restrict__ Y0t,
                                             int n, int feat) {
    const int b   = blockIdx.x;
    const int tid = threadIdx.x;
    if (b < n) {
        __shared__ float red[256];
        const float4* row4 = (const float4*)(A + (size_t)b * n);
        float acc = 0.f;
        for (int j = tid; j < n / 4; j += 256) {
            float4 a = row4[j];
            acc += (a.x + a.y) + (a.z + a.w);
        }
        red[tid] = acc; __syncthreads();
        #pragma unroll
        for (int w = 128; w > 0; w >>= 1) {
            if (tid < w) red[tid] += red[tid + w];
            __syncthreads();
        }
        if (tid == 0) {
            float deg = red[0];
            s[b] = (deg > 0.f) ? rsqrtf(deg) : 0.f;
        }
    } else {
        const int i = b - n;
        float acc[GCNW];
        #pragma unroll
        for (int o = 0; o < GCNW; ++o) acc[o] = 0.f;
        const float* xr = X + (size_t)i * feat;
        for (int j = tid; j < feat; j += 256) {
            float xv = xr[j];
            #pragma unroll
            for (int o = 0; o < GCNW; ++o) acc[o] = fmaf(xv, W0[o * feat + j], acc[o]);
        }
        #pragma unroll
        for (int o = 0; o < GCNW; ++o) {
            float v = acc[o];
            #pragma unroll
            for (int off = 32; off > 0; off >>= 1) v += __shfl_xor(v, off);
            acc[o] = v;
        }
        __shared__ float part[4][GCNW];
        const int wv = tid >> 6, ln = tid & 63;
        if (ln == 0) {
            #pragma unroll
            for (int o = 0; o < GCNW; ++o) part[wv][o] = acc[o];
        }
        __syncthreads();
        if (tid < GCNW)
            Y0t[(size_t)tid * n + i] =
                part[0][tid] + part[1][tid] + part[2][tid] + part[3][tid];
    }
}

// ---- k_ap: z = selu(s_i*(sum_j A_ij s_j Y_j + s_i Y_i)); if W: fuse next
//      layer matvec, write (10,n); else write z. rowmajor: write (n,10). ----
__global__ __launch_bounds__(256) void k_ap(const float* __restrict__ A,
                                            const float* __restrict__ s,
                                            const float* __restrict__ Yt,
                                            const float* __restrict__ W,   // (10,10) or null
                                            float* __restrict__ Ot, int n,
                                            int rowmajor) {
    const int i   = blockIdx.x;
    const int tid = threadIdx.x;
    float acc[GCNW];
    #pragma unroll
    for (int o = 0; o < GCNW; ++o) acc[o] = 0.f;
    const float4* a4 = (const float4*)(A + (size_t)i * n);
    const float4* s4 = (const float4*)s;
    for (int j4 = tid; j4 < n / 4; j4 += 256) {
        float4 a  = a4[j4];
        float4 sv = s4[j4];
        a.x *= sv.x; a.y *= sv.y; a.z *= sv.z; a.w *= sv.w;
        #pragma unroll
        for (int o = 0; o < GCNW; ++o) {
            float4 y = ((const float4*)(Yt + (size_t)o * n))[j4];
            acc[o] = fmaf(a.x, y.x, acc[o]);
            acc[o] = fmaf(a.y, y.y, acc[o]);
            acc[o] = fmaf(a.z, y.z, acc[o]);
            acc[o] = fmaf(a.w, y.w, acc[o]);
        }
    }
    #pragma unroll
    for (int o = 0; o < GCNW; ++o) {
        float v = acc[o];
        #pragma unroll
        for (int off = 32; off > 0; off >>= 1) v += __shfl_xor(v, off);
        acc[o] = v;
    }
    __shared__ float part[4][GCNW];
    __shared__ float zsh[GCNW];
    const int wv = tid >> 6, ln = tid & 63;
    if (ln == 0) {
        #pragma unroll
        for (int o = 0; o < GCNW; ++o) part[wv][o] = acc[o];
    }
    __syncthreads();
    if (tid < GCNW) {
        float dot = part[0][tid] + part[1][tid] + part[2][tid] + part[3][tid];
        float si  = s[i];
        float z   = selu_f(si * (dot + si * Yt[(size_t)tid * n + i]));
        if (W) zsh[tid] = z;
        else if (rowmajor) Ot[(size_t)i * GCNW + tid] = z;
        else               Ot[(size_t)tid * n + i]    = z;
    }
    if (W) {
        __syncthreads();
        if (tid < GCNW) {
            float d = 0.f;
            #pragma unroll
            for (int u = 0; u < GCNW; ++u) d = fmaf(zsh[u], W[tid * GCNW + u], d);
            Ot[(size_t)tid * n + i] = d;
        }
    }
}

// ---------------------------------------------------------------------------
// Single-wave LSTM. quad u = lane>>2 (unit slot: d=u/5, unit=u%5); gt=lane&3
// in {i,f,g,o}. Weights pre-scaled by -log2e (sig) / -2log2e (tanh) so the
// activation is a raw exp2. c carried pre-scaled by -2log2e. hn valid on
// gt==0 lanes; broadcast sets are SGPR (readlane).
// ---------------------------------------------------------------------------
struct SB { float v[GCNW]; };

__device__ __forceinline__ SB bc(float x) {
    SB r;
    #pragma unroll
    for (int j = 0; j < GCNW; ++j) r.v[j] = rl(x, 4 * j);
    return r;
}

__device__ __forceinline__ SB loadrow(const float* __restrict__ p) {
    SB r;
    #pragma unroll
    for (int j = 0; j < GCNW; ++j) r.v[j] = p[j];
    return r;
}

__device__ __forceinline__ float stage(const float (&wi)[GCNW], const float (&wh)[GCNW],
                                       float bias, const SB& x, const SB& h,
                                       float& cS, float P, float Qn) {
    float a0 = bias, a1 = 0.f, a2 = 0.f, a3 = 0.f;
    #pragma unroll
    for (int j = 0; j < GCNW; j += 2) {
        a0 = fmaf(wi[j],     x.v[j],     a0);
        a1 = fmaf(wi[j + 1], x.v[j + 1], a1);
        a2 = fmaf(wh[j],     h.v[j],     a2);
        a3 = fmaf(wh[j + 1], h.v[j + 1], a3);
    }
    float acc = (a0 + a1) + (a2 + a3);        // pre-scaled preactivation
    float e   = fexp2(acc);
    float r   = frcp(1.f + e);
    float tg  = fmaf(Qn, e, P);               // sig lanes: 1 ; g lanes: -2log2e*(1-e)
    float av  = tg * r;                       // sig(a) or -2log2e*tanh(a)
    float fv  = qb<1>(av), gv = qb<2>(av), ov = qb<3>(av);
    float cn  = fmaf(fv, cS, av * gv);        // scaled c', valid on gt==0
    cS = cn;
    float e2  = fexp2(cn);                    // exp(-2*c_true)
    float r2  = frcp(1.f + e2);
    float t1  = fmaf(-ov, e2, ov);            // ov*(1-e2)
    return t1 * r2;                           // hn = ov*tanh(c_true)
}

__global__ __launch_bounds__(64, 1) void k_lstm(
    const float* __restrict__ Hr,    // (n,10) encode inputs, row-major
    const float* __restrict__ W_ih,  // (6,20,10)
    const float* __restrict__ W_hh,  // (6,20,5)
    const float* __restrict__ b_ih,  // (6,20)
    const float* __restrict__ b_hh,  // (6,20)
    const float* __restrict__ h0,    // (6,5)
    const float* __restrict__ c0,    // (6,5)
    const float* __restrict__ tok,   // (10)
    const float* __restrict__ Wo,    // (10)
    const float* __restrict__ bo,    // (1)
    float* __restrict__ out, int n)
{
    const int  lane = threadIdx.x;
    const int  ul   = lane >> 2, gt = lane & 3;
    const bool actl = ul < GCNW;               // lanes 0..39
    const int  ulc  = actl ? ul : 0;
    const int  dd   = ulc / 5, un = ulc % 5;
    const int  row  = gt * 5 + un;             // torch gate order i,f,g,o
    const bool isg  = (gt == 2);
    const float c2e = isg ? (-2.f * LOG2E) : (-LOG2E);
    const float P   = isg ? (-2.f * LOG2E) : 1.f;
    const float Qn  = isg ? ( 2.f * LOG2E) : 0.f;

    float wih[3][GCNW], whh[3][GCNW], bias[3], hv[3], cS[3];
    #pragma unroll
    for (int l = 0; l < 3; ++l) {
        const int k = 2 * l + dd;
        #pragma unroll
        for (int j = 0; j < GCNW; ++j)
            wih[l][j] = actl ? c2e * W_ih[(k * 20 + row) * 10 + j] : 0.f;
        #pragma unroll
        for (int j = 0; j < GCNW; ++j)
            whh[l][j] = (actl && (j / 5) == dd) ? c2e * W_hh[(k * 20 + row) * 5 + (j % 5)] : 0.f;
        bias[l] = actl ? c2e * (b_ih[k * 20 + row] + b_hh[k * 20 + row]) : 0.f;
        hv[l]   = actl ? h0[k * 5 + un] : 0.f;
        cS[l]   = actl ? (-2.f * LOG2E) * c0[k * 5 + un] : 0.f;
    }

    SB B0 = bc(hv[0]), B1 = bc(hv[1]), B2 = bc(hv[2]);

    // ---- encode: peeled prologue, branch-free steady loop, epilogue -------
    {   // t = 0
        SB X = loadrow(Hr);
        float n0 = stage(wih[0], whh[0], bias[0], X, B0, cS[0], P, Qn);
        B0 = bc(n0);
    }
    {   // t = 1
        SB X = loadrow(Hr + GCNW);
        float n0 = stage(wih[0], whh[0], bias[0], X,  B0, cS[0], P, Qn);
        float n1 = stage(wih[1], whh[1], bias[1], B0, B1, cS[1], P, Qn);
        B0 = bc(n0); B1 = bc(n1);
    }
    SB Xc = loadrow(Hr + 2 * GCNW);
    #pragma unroll 1
    for (int t = 2; t < n; ++t) {
        const int tn = (t + 1 < n) ? t + 1 : t;        // uniform select, no branch
        SB Xn = loadrow(Hr + (size_t)tn * GCNW);
        float n0 = stage(wih[0], whh[0], bias[0], Xc, B0, cS[0], P, Qn);
        float n1 = stage(wih[1], whh[1], bias[1], B0, B1, cS[1], P, Qn);
        float n2 = stage(wih[2], whh[2], bias[2], B1, B2, cS[2], P, Qn);
        B0 = bc(n0); B1 = bc(n1); B2 = bc(n2);
        Xc = Xn;
    }
    {   // epilogue: finish layers 1,2
        float p1 = stage(wih[1], whh[1], bias[1], B0, B1, cS[1], P, Qn);
        float p2 = stage(wih[2], whh[2], bias[2], B1, B2, cS[2], P, Qn);
        B1 = bc(p1); B2 = bc(p2);
        float q2 = stage(wih[2], whh[2], bias[2], B1, B2, cS[2], P, Qn);
        B2 = bc(q2);
    }

    // ---- decode: nested 64x64, branch-free inner body ---------------------
    float wo[GCNW];
    #pragma unroll
    for (int j = 0; j < GCNW; ++j) wo[j] = -LOG2E * Wo[j];
    const float bos = -LOG2E * bo[0];
    SB X = loadrow(tok);

    #pragma unroll 1
    for (int t64 = 0; t64 < n / 64; ++t64) {
        float ob = 0.f;
        #pragma unroll 1
        for (int tt = 0; tt < 64; ++tt) {
            float n0 = stage(wih[0], whh[0], bias[0], X,  B0, cS[0], P, Qn);
            B0 = bc(n0);
            float n1 = stage(wih[1], whh[1], bias[1], B0, B1, cS[1], P, Qn);
            B1 = bc(n1);
            float n2 = stage(wih[2], whh[2], bias[2], B1, B2, cS[2], P, Qn);
            B2 = bc(n2);
            float dot = bos;
            #pragma unroll
            for (int j = 0; j < GCNW; ++j) dot = fmaf(wo[j], B2.v[j], dot);
            float val = frcp(1.f + fexp2(dot));
            ob = (lane == tt) ? val : ob;     // cndmask, no branch
            X = B2;                           // SALU copies, off VALU chain
        }
        out[t64 * 64 + lane] = ob;
    }
}

extern "C" void kernel_launch(void* const* d_in, const int* in_sizes, int n_in,
                              void* d_out, int out_size, void* d_ws, size_t ws_size,
                              hipStream_t stream) {
    const float* A    = (const float*)d_in[0];
    const float* X    = (const float*)d_in[1];
    const float* W0   = (const float*)d_in[2];
    const float* W1   = (const float*)d_in[3];
    const float* W2   = (const float*)d_in[4];
    const float* W_ih = (const float*)d_in[5];
    const float* W_hh = (const float*)d_in[6];
    const float* b_ih = (const float*)d_in[7];
    const float* b_hh = (const float*)d_in[8];
    const float* h0   = (const float*)d_in[9];
    const float* c0   = (const float*)d_in[10];
    const float* tok  = (const float*)d_in[11];
    const float* Wo   = (const float*)d_in[12];
    const float* bo   = (const float*)d_in[13];
    float* out = (float*)d_out;

    const int n    = out_size;            // 4096
    const int feat = in_sizes[1] / n;     // 1024

    // workspace: s (n) | P0 (10n) | P1 (10n)
    float* s  = (float*)d_ws;
    float* P0 = s + n;
    float* P1 = P0 + (size_t)n * GCNW;

    k_pre<<<2 * n, 256, 0, stream>>>(A, X, W0, s, P0, n, feat);        // s, Y0t
    k_ap <<<n,     256, 0, stream>>>(A, s, P0, W1,      P1, n, 0);     // Y1t (10,n)
    k_ap <<<n,     256, 0, stream>>>(A, s, P1, W2,      P0, n, 0);     // Y2t (10,n)
    k_ap <<<n,     256, 0, stream>>>(A, s, P0, nullptr, P1, n, 1);     // H  (n,10)
    k_lstm<<<1, 64, 0, stream>>>(P1, W_ih, W_hh, b_ih, b_hh, h0, c0,
                                 tok, Wo, bo, out, n);
}

// Round 4
// 2764.179 us; speedup vs baseline: 1.8068x; 1.1990x over previous
//
#include <hip/hip_runtime.h>
#include <math.h>

// ---------------------------------------------------------------------------
// GraphConvNetLSTM: GCN (3 layers, reassociated Ahat@(H@W.T)) + 3-layer bidir
// LSTM. Encode: 3 waves, one per layer, software-pipelined over 32-step
// chunks via double-buffered LDS (wave w runs chunk p-w in phase p).
// Decode: single wave, branch-free, autoregressive (true serial chain).
// DPP quad-gather, SGPR broadcasts, activation scales folded into weights.
// ---------------------------------------------------------------------------

#define GCNW 10
#define LOG2E 1.4426950408889634f
#define CHK  32      // pipeline chunk (timesteps)
#define CROW 12      // padded LDS row stride (floats) -> 48B, keeps b128 align

__device__ __forceinline__ float rl(float v, int l) {
    return __int_as_float(__builtin_amdgcn_readlane(__float_as_int(v), l));
}
__device__ __forceinline__ float frcp(float x) { return __builtin_amdgcn_rcpf(x); }

#if __has_builtin(__builtin_amdgcn_exp2f)
__device__ __forceinline__ float fexp2(float x) { return __builtin_amdgcn_exp2f(x); }
#else
__device__ __forceinline__ float fexp2(float x) { return __expf(x * 0.6931471805599453f); }
#endif

// quad_perm broadcast: lane (quad_base + L) -> all 4 lanes of the quad
template <int L>
__device__ __forceinline__ float qb(float v) {
    constexpr int ctrl = L | (L << 2) | (L << 4) | (L << 6);
    int r = __builtin_amdgcn_update_dpp(0, __float_as_int(v), ctrl, 0xF, 0xF, true);
    return __int_as_float(r);
}

__device__ __forceinline__ float selu_f(float x) {
    const float lam = 1.0507009873554805f;
    const float la  = 1.7580993408473766f;   // lam * alpha
    return x > 0.f ? lam * x : la * (__expf(x) - 1.f);
}

// ---- k_pre: blocks [0,n) rowsum->s ; blocks [n,2n) Y0t[o][i] = X[i]@W0.T ---
__global__ __launch_bounds__(256) void k_pre(const float* __restrict__ A,
                                             const float* __restrict__ X,
                                             const float* __restrict__ W0,
                                             float* __restrict__ s,
                                             float* __restrict__ Y0t,
                                             int n, int feat) {
    const int b   = blockIdx.x;
    const int tid = threadIdx.x;
    if (b < n) {
        __shared__ float red[256];
        const float4* row4 = (const float4*)(A + (size_t)b * n);
        float acc = 0.f;
        for (int j = tid; j < n / 4; j += 256) {
            float4 a = row4[j];
            acc += (a.x + a.y) + (a.z + a.w);
        }
        red[tid] = acc; __syncthreads();
        #pragma unroll
        for (int w = 128; w > 0; w >>= 1) {
            if (tid < w) red[tid] += red[tid + w];
            __syncthreads();
        }
        if (tid == 0) {
            float deg = red[0];
            s[b] = (deg > 0.f) ? rsqrtf(deg) : 0.f;
        }
    } else {
        const int i = b - n;
        float acc[GCNW];
        #pragma unroll
        for (int o = 0; o < GCNW; ++o) acc[o] = 0.f;
        const float* xr = X + (size_t)i * feat;
        for (int j = tid; j < feat; j += 256) {
            float xv = xr[j];
            #pragma unroll
            for (int o = 0; o < GCNW; ++o) acc[o] = fmaf(xv, W0[o * feat + j], acc[o]);
        }
        #pragma unroll
        for (int o = 0; o < GCNW; ++o) {
            float v = acc[o];
            #pragma unroll
            for (int off = 32; off > 0; off >>= 1) v += __shfl_xor(v, off);
            acc[o] = v;
        }
        __shared__ float part[4][GCNW];
        const int wv = tid >> 6, ln = tid & 63;
        if (ln == 0) {
            #pragma unroll
            for (int o = 0; o < GCNW; ++o) part[wv][o] = acc[o];
        }
        __syncthreads();
        if (tid < GCNW)
            Y0t[(size_t)tid * n + i] =
                part[0][tid] + part[1][tid] + part[2][tid] + part[3][tid];
    }
}

// ---- k_ap: z = selu(s_i*(sum_j A_ij s_j Y_j + s_i Y_i)); if W: fuse next
//      layer matvec, write (10,n); else write z. rowmajor: write (n,10). ----
__global__ __launch_bounds__(256) void k_ap(const float* __restrict__ A,
                                            const float* __restrict__ s,
                                            const float* __restrict__ Yt,
                                            const float* __restrict__ W,   // (10,10) or null
                                            float* __restrict__ Ot, int n,
                                            int rowmajor) {
    const int i   = blockIdx.x;
    const int tid = threadIdx.x;
    float acc[GCNW];
    #pragma unroll
    for (int o = 0; o < GCNW; ++o) acc[o] = 0.f;
    const float4* a4 = (const float4*)(A + (size_t)i * n);
    const float4* s4 = (const float4*)s;
    for (int j4 = tid; j4 < n / 4; j4 += 256) {
        float4 a  = a4[j4];
        float4 sv = s4[j4];
        a.x *= sv.x; a.y *= sv.y; a.z *= sv.z; a.w *= sv.w;
        #pragma unroll
        for (int o = 0; o < GCNW; ++o) {
            float4 y = ((const float4*)(Yt + (size_t)o * n))[j4];
            acc[o] = fmaf(a.x, y.x, acc[o]);
            acc[o] = fmaf(a.y, y.y, acc[o]);
            acc[o] = fmaf(a.z, y.z, acc[o]);
            acc[o] = fmaf(a.w, y.w, acc[o]);
        }
    }
    #pragma unroll
    for (int o = 0; o < GCNW; ++o) {
        float v = acc[o];
        #pragma unroll
        for (int off = 32; off > 0; off >>= 1) v += __shfl_xor(v, off);
        acc[o] = v;
    }
    __shared__ float part[4][GCNW];
    __shared__ float zsh[GCNW];
    const int wv = tid >> 6, ln = tid & 63;
    if (ln == 0) {
        #pragma unroll
        for (int o = 0; o < GCNW; ++o) part[wv][o] = acc[o];
    }
    __syncthreads();
    if (tid < GCNW) {
        float dot = part[0][tid] + part[1][tid] + part[2][tid] + part[3][tid];
        float si  = s[i];
        float z   = selu_f(si * (dot + si * Yt[(size_t)tid * n + i]));
        if (W) zsh[tid] = z;
        else if (rowmajor) Ot[(size_t)i * GCNW + tid] = z;
        else               Ot[(size_t)tid * n + i]    = z;
    }
    if (W) {
        __syncthreads();
        if (tid < GCNW) {
            float d = 0.f;
            #pragma unroll
            for (int u = 0; u < GCNW; ++u) d = fmaf(zsh[u], W[tid * GCNW + u], d);
            Ot[(size_t)tid * n + i] = d;
        }
    }
}

// ---------------------------------------------------------------------------
// LSTM kernel: 3 waves. Per-wave lane layout: quad u = lane>>2 (unit slot:
// d=u/5, unit=u%5, matching concat [dir0,dir1]); gt=lane&3 in {i,f,g,o}.
// Weights pre-scaled by -log2e (sig) / -2log2e (tanh); c carried pre-scaled.
// ---------------------------------------------------------------------------
struct SB { float v[GCNW]; };

__device__ __forceinline__ SB bc(float x) {
    SB r;
    #pragma unroll
    for (int j = 0; j < GCNW; ++j) r.v[j] = rl(x, 4 * j);
    return r;
}

__device__ __forceinline__ SB loadrow(const float* __restrict__ p) {
    SB r;
    #pragma unroll
    for (int j = 0; j < GCNW; ++j) r.v[j] = p[j];
    return r;
}

// uniform-address LDS row read (16B-aligned base, CROW=12 floats stride)
__device__ __forceinline__ SB ldsrow(const float* p) {
    SB r;
    float4 a = ((const float4*)p)[0];
    float4 b = ((const float4*)p)[1];
    float2 c = *(const float2*)(p + 8);
    r.v[0]=a.x; r.v[1]=a.y; r.v[2]=a.z; r.v[3]=a.w;
    r.v[4]=b.x; r.v[5]=b.y; r.v[6]=b.z; r.v[7]=b.w;
    r.v[8]=c.x; r.v[9]=c.y;
    return r;
}

__device__ __forceinline__ float stage(const float (&wi)[GCNW], const float (&wh)[GCNW],
                                       float bias, const SB& x, const SB& h,
                                       float& cS, float P, float Qn) {
    // h-side first (operands available earliest), x-side second
    float a2 = 0.f, a3 = 0.f, a0 = bias, a1 = 0.f;
    #pragma unroll
    for (int j = 0; j < GCNW; j += 2) {
        a2 = fmaf(wh[j],     h.v[j],     a2);
        a3 = fmaf(wh[j + 1], h.v[j + 1], a3);
    }
    #pragma unroll
    for (int j = 0; j < GCNW; j += 2) {
        a0 = fmaf(wi[j],     x.v[j],     a0);
        a1 = fmaf(wi[j + 1], x.v[j + 1], a1);
    }
    float acc = (a0 + a1) + (a2 + a3);        // pre-scaled preactivation
    float e   = fexp2(acc);
    float r   = frcp(1.f + e);
    float tg  = fmaf(Qn, e, P);               // sig lanes: 1 ; g lanes: -2log2e*(1-e)
    float av  = tg * r;                       // sig(a) or -2log2e*tanh(a)
    float fv  = qb<1>(av), gv = qb<2>(av), ov = qb<3>(av);
    float cn  = fmaf(fv, cS, av * gv);        // scaled c', valid on gt==0
    cS = cn;
    float e2  = fexp2(cn);                    // exp(-2*c_true)
    float r2  = frcp(1.f + e2);
    float t1  = fmaf(-ov, e2, ov);            // ov*(1-e2)
    return t1 * r2;                           // hn = ov*tanh(c_true)
}

__global__ __launch_bounds__(192, 1) void k_lstm(
    const float* __restrict__ Hr,    // (n,10) encode inputs, row-major
    const float* __restrict__ W_ih,  // (6,20,10)
    const float* __restrict__ W_hh,  // (6,20,5)
    const float* __restrict__ b_ih,  // (6,20)
    const float* __restrict__ b_hh,  // (6,20)
    const float* __restrict__ h0,    // (6,5)
    const float* __restrict__ c0,    // (6,5)
    const float* __restrict__ tok,   // (10)
    const float* __restrict__ Wo,    // (10)
    const float* __restrict__ bo,    // (1)
    float* __restrict__ out, int n)
{
    __shared__ __align__(16) float buf0[2][CHK * CROW];  // layer0 -> layer1
    __shared__ __align__(16) float buf1[2][CHK * CROW];  // layer1 -> layer2
    __shared__ float stg[2][2][GCNW];                    // final (h,cS) of layers 1,2

    const int  lane = threadIdx.x & 63;
    const int  wid  = threadIdx.x >> 6;        // 0..2 = layer
    const int  ul   = lane >> 2, gt = lane & 3;
    const bool actl = ul < GCNW;               // lanes 0..39
    const bool wl10 = actl && (gt == 0);       // writer lanes (one per unit)
    const int  ulc  = actl ? ul : 0;
    const int  dd   = ulc / 5, un = ulc % 5;
    const int  row  = gt * 5 + un;             // torch gate order i,f,g,o
    const bool isg  = (gt == 2);
    const float c2e = isg ? (-2.f * LOG2E) : (-LOG2E);
    const float P   = isg ? (-2.f * LOG2E) : 1.f;
    const float Qn  = isg ? ( 2.f * LOG2E) : 0.f;

    float wih[3][GCNW], whh[3][GCNW], bias[3], hv[3], cS[3];
    #pragma unroll
    for (int l = 0; l < 3; ++l) {
        const int k = 2 * l + dd;
        #pragma unroll
        for (int j = 0; j < GCNW; ++j)
            wih[l][j] = actl ? c2e * W_ih[(k * 20 + row) * 10 + j] : 0.f;
        #pragma unroll
        for (int j = 0; j < GCNW; ++j)
            whh[l][j] = (actl && (j / 5) == dd) ? c2e * W_hh[(k * 20 + row) * 5 + (j % 5)] : 0.f;
        bias[l] = actl ? c2e * (b_ih[k * 20 + row] + b_hh[k * 20 + row]) : 0.f;
        hv[l]   = actl ? h0[k * 5 + un] : 0.f;
        cS[l]   = actl ? (-2.f * LOG2E) * c0[k * 5 + un] : 0.f;
    }

    SB B0 = bc(hv[0]), B1 = bc(hv[1]), B2 = bc(hv[2]);
    float h1l = 0.f, h2l = 0.f;                 // last hn (waves 1,2)

    // ---- encode: 3-wave pipeline over chunks ------------------------------
    const int NCH = n / CHK;
    #pragma unroll 1
    for (int p = 0; p < NCH + 2; ++p) {
        const int ck = p - wid;
        if (ck >= 0 && ck < NCH) {
            if (wid == 0) {
                float* wb = buf0[ck & 1];
                const int t0 = ck * CHK;
                SB Xc = loadrow(Hr + (size_t)t0 * GCNW);
                #pragma unroll 1
                for (int tt = 0; tt < CHK; ++tt) {
                    const int t  = t0 + tt;
                    const int tn = (t + 1 < n) ? t + 1 : t;
                    SB Xn = loadrow(Hr + (size_t)tn * GCNW);
                    float nh = stage(wih[0], whh[0], bias[0], Xc, B0, cS[0], P, Qn);
                    B0 = bc(nh);
                    if (wl10) wb[tt * CROW + ul] = nh;
                    Xc = Xn;
                }
            } else if (wid == 1) {
                const float* rb = buf0[ck & 1];
                float*       wb = buf1[ck & 1];
                SB Xc = ldsrow(rb);
                #pragma unroll 1
                for (int tt = 0; tt < CHK; ++tt) {
                    const int tp = (tt + 1 < CHK) ? tt + 1 : tt;
                    SB Xn = ldsrow(rb + tp * CROW);
                    float nh = stage(wih[1], whh[1], bias[1], Xc, B1, cS[1], P, Qn);
                    B1 = bc(nh); h1l = nh;
                    if (wl10) wb[tt * CROW + ul] = nh;
                    Xc = Xn;
                }
            } else {
                const float* rb = buf1[ck & 1];
                SB Xc = ldsrow(rb);
                #pragma unroll 1
                for (int tt = 0; tt < CHK; ++tt) {
                    const int tp = (tt + 1 < CHK) ? tt + 1 : tt;
                    SB Xn = ldsrow(rb + tp * CROW);
                    float nh = stage(wih[2], whh[2], bias[2], Xc, B2, cS[2], P, Qn);
                    B2 = bc(nh); h2l = nh;
                    Xc = Xn;
                }
            }
        }
        __syncthreads();
    }

    // ---- hand final (h,cS) of layers 1,2 to wave 0 ------------------------
    if (wid == 1 && wl10) { stg[0][0][ul] = h1l; stg[0][1][ul] = cS[1]; }
    if (wid == 2 && wl10) { stg[1][0][ul] = h2l; stg[1][1][ul] = cS[2]; }
    __syncthreads();
    if (wid != 0) return;

    {
        float h1 = stg[0][0][ulc]; cS[1] = stg[0][1][ulc];
        float h2 = stg[1][0][ulc]; cS[2] = stg[1][1][ulc];
        B1 = bc(h1); B2 = bc(h2);
    }

    // ---- decode: single wave, nested 64x64, branch-free inner body --------
    float wo[GCNW];
    #pragma unroll
    for (int j = 0; j < GCNW; ++j) wo[j] = -LOG2E * Wo[j];
    const float bos = -LOG2E * bo[0];
    SB X = loadrow(tok);

    #pragma unroll 1
    for (int t64 = 0; t64 < n / 64; ++t64) {
        float ob = 0.f;
        #pragma unroll 1
        for (int tt = 0; tt < 64; ++tt) {
            float n0 = stage(wih[0], whh[0], bias[0], X,  B0, cS[0], P, Qn);
            B0 = bc(n0);
            float n1 = stage(wih[1], whh[1], bias[1], B0, B1, cS[1], P, Qn);
            B1 = bc(n1);
            float n2 = stage(wih[2], whh[2], bias[2], B1, B2, cS[2], P, Qn);
            B2 = bc(n2);
            X = B2;
            float d0 = bos, d1 = 0.f;
            #pragma unroll
            for (int j = 0; j < GCNW; j += 2) {
                d0 = fmaf(wo[j],     B2.v[j],     d0);
                d1 = fmaf(wo[j + 1], B2.v[j + 1], d1);
            }
            float val = frcp(1.f + fexp2(d0 + d1));
            ob = (lane == tt) ? val : ob;     // cndmask, no branch
        }
        out[t64 * 64 + lane] = ob;
    }
}

extern "C" void kernel_launch(void* const* d_in, const int* in_sizes, int n_in,
                              void* d_out, int out_size, void* d_ws, size_t ws_size,
                              hipStream_t stream) {
    const float* A    = (const float*)d_in[0];
    const float* X    = (const float*)d_in[1];
    const float* W0   = (const float*)d_in[2];
    const float* W1   = (const float*)d_in[3];
    const float* W2   = (const float*)d_in[4];
    const float* W_ih = (const float*)d_in[5];
    const float* W_hh = (const float*)d_in[6];
    const float* b_ih = (const float*)d_in[7];
    const float* b_hh = (const float*)d_in[8];
    const float* h0   = (const float*)d_in[9];
    const float* c0   = (const float*)d_in[10];
    const float* tok  = (const float*)d_in[11];
    const float* Wo   = (const float*)d_in[12];
    const float* bo   = (const float*)d_in[13];
    float* out = (float*)d_out;

    const int n    = out_size;            // 4096
    const int feat = in_sizes[1] / n;     // 1024

    // workspace: s (n) | P0 (10n) | P1 (10n)
    float* s  = (float*)d_ws;
    float* P0 = s + n;
    float* P1 = P0 + (size_t)n * GCNW;

    k_pre<<<2 * n, 256, 0, stream>>>(A, X, W0, s, P0, n, feat);        // s, Y0t
    k_ap <<<n,     256, 0, stream>>>(A, s, P0, W1,      P1, n, 0);     // Y1t (10,n)
    k_ap <<<n,     256, 0, stream>>>(A, s, P1, W2,      P0, n, 0);     // Y2t (10,n)
    k_ap <<<n,     256, 0, stream>>>(A, s, P0, nullptr, P1, n, 1);     // H  (n,10)
    k_lstm<<<1, 192, 0, stream>>>(P1, W_ih, W_hh, b_ih, b_hh, h0, c0,
                                  tok, Wo, bo, out, n);
}

// Round 5
// 2739.028 us; speedup vs baseline: 1.8233x; 1.0092x over previous
//
#include <hip/hip_runtime.h>
#include <math.h>

// ---------------------------------------------------------------------------
// GraphConvNetLSTM: GCN (3 layers, reassociated Ahat@(H@W.T)) + 3-layer bidir
// LSTM. k_enc: 3 waves (one per layer) pipelined over 32-step chunks via
// double-buffered LDS; x-side dot precomputed one step ahead (off-chain).
// k_dec: 1 wave, autoregressive; h-side dots carried off-chain (hp pipeline).
// Serial chain per stage = dot(depth 5) + activation only.
// ---------------------------------------------------------------------------

#define GCNW 10
#define LOG2E 1.4426950408889634f
#define CHK  32      // pipeline chunk (timesteps)
#define CROW 12      // padded LDS row stride (floats)

__device__ __forceinline__ float rl(float v, int l) {
    return __int_as_float(__builtin_amdgcn_readlane(__float_as_int(v), l));
}
__device__ __forceinline__ float frcp(float x) { return __builtin_amdgcn_rcpf(x); }

#if __has_builtin(__builtin_amdgcn_exp2f)
__device__ __forceinline__ float fexp2(float x) { return __builtin_amdgcn_exp2f(x); }
#else
__device__ __forceinline__ float fexp2(float x) { return __expf(x * 0.6931471805599453f); }
#endif

template <int L>
__device__ __forceinline__ float qb(float v) {
    constexpr int ctrl = L | (L << 2) | (L << 4) | (L << 6);
    int r = __builtin_amdgcn_update_dpp(0, __float_as_int(v), ctrl, 0xF, 0xF, true);
    return __int_as_float(r);
}

__device__ __forceinline__ float selu_f(float x) {
    const float lam = 1.0507009873554805f;
    const float la  = 1.7580993408473766f;
    return x > 0.f ? lam * x : la * (__expf(x) - 1.f);
}

// ---- k_pre: blocks [0,n) rowsum->s ; blocks [n,2n) Y0t[o][i] = X[i]@W0.T ---
__global__ __launch_bounds__(256) void k_pre(const float* __restrict__ A,
                                             const float* __restrict__ X,
                                             const float* __restrict__ W0,
                                             float* __restrict__ s,
                                             float* __restrict__ Y0t,
                                             int n, int feat) {
    const int b   = blockIdx.x;
    const int tid = threadIdx.x;
    if (b < n) {
        __shared__ float red[256];
        const float4* row4 = (const float4*)(A + (size_t)b * n);
        float acc = 0.f;
        for (int j = tid; j < n / 4; j += 256) {
            float4 a = row4[j];
            acc += (a.x + a.y) + (a.z + a.w);
        }
        red[tid] = acc; __syncthreads();
        #pragma unroll
        for (int w = 128; w > 0; w >>= 1) {
            if (tid < w) red[tid] += red[tid + w];
            __syncthreads();
        }
        if (tid == 0) {
            float deg = red[0];
            s[b] = (deg > 0.f) ? rsqrtf(deg) : 0.f;
        }
    } else {
        const int i = b - n;
        float acc[GCNW];
        #pragma unroll
        for (int o = 0; o < GCNW; ++o) acc[o] = 0.f;
        const float* xr = X + (size_t)i * feat;
        for (int j = tid; j < feat; j += 256) {
            float xv = xr[j];
            #pragma unroll
            for (int o = 0; o < GCNW; ++o) acc[o] = fmaf(xv, W0[o * feat + j], acc[o]);
        }
        #pragma unroll
        for (int o = 0; o < GCNW; ++o) {
            float v = acc[o];
            #pragma unroll
            for (int off = 32; off > 0; off >>= 1) v += __shfl_xor(v, off);
            acc[o] = v;
        }
        __shared__ float part[4][GCNW];
        const int wv = tid >> 6, ln = tid & 63;
        if (ln == 0) {
            #pragma unroll
            for (int o = 0; o < GCNW; ++o) part[wv][o] = acc[o];
        }
        __syncthreads();
        if (tid < GCNW)
            Y0t[(size_t)tid * n + i] =
                part[0][tid] + part[1][tid] + part[2][tid] + part[3][tid];
    }
}

// ---- k_ap: z = selu(s_i*(sum_j A_ij s_j Y_j + s_i Y_i)); if W: fuse next
//      layer matvec, write (10,n); else write z (rowmajor -> (n,10)). -------
__global__ __launch_bounds__(256) void k_ap(const float* __restrict__ A,
                                            const float* __restrict__ s,
                                            const float* __restrict__ Yt,
                                            const float* __restrict__ W,
                                            float* __restrict__ Ot, int n,
                                            int rowmajor) {
    const int i   = blockIdx.x;
    const int tid = threadIdx.x;
    float acc[GCNW];
    #pragma unroll
    for (int o = 0; o < GCNW; ++o) acc[o] = 0.f;
    const float4* a4 = (const float4*)(A + (size_t)i * n);
    const float4* s4 = (const float4*)s;
    for (int j4 = tid; j4 < n / 4; j4 += 256) {
        float4 a  = a4[j4];
        float4 sv = s4[j4];
        a.x *= sv.x; a.y *= sv.y; a.z *= sv.z; a.w *= sv.w;
        #pragma unroll
        for (int o = 0; o < GCNW; ++o) {
            float4 y = ((const float4*)(Yt + (size_t)o * n))[j4];
            acc[o] = fmaf(a.x, y.x, acc[o]);
            acc[o] = fmaf(a.y, y.y, acc[o]);
            acc[o] = fmaf(a.z, y.z, acc[o]);
            acc[o] = fmaf(a.w, y.w, acc[o]);
        }
    }
    #pragma unroll
    for (int o = 0; o < GCNW; ++o) {
        float v = acc[o];
        #pragma unroll
        for (int off = 32; off > 0; off >>= 1) v += __shfl_xor(v, off);
        acc[o] = v;
    }
    __shared__ float part[4][GCNW];
    __shared__ float zsh[GCNW];
    const int wv = tid >> 6, ln = tid & 63;
    if (ln == 0) {
        #pragma unroll
        for (int o = 0; o < GCNW; ++o) part[wv][o] = acc[o];
    }
    __syncthreads();
    if (tid < GCNW) {
        float dot = part[0][tid] + part[1][tid] + part[2][tid] + part[3][tid];
        float si  = s[i];
        float z   = selu_f(si * (dot + si * Yt[(size_t)tid * n + i]));
        if (W) zsh[tid] = z;
        else if (rowmajor) Ot[(size_t)i * GCNW + tid] = z;
        else               Ot[(size_t)tid * n + i]    = z;
    }
    if (W) {
        __syncthreads();
        if (tid < GCNW) {
            float d = 0.f;
            #pragma unroll
            for (int u = 0; u < GCNW; ++u) d = fmaf(zsh[u], W[tid * GCNW + u], d);
            Ot[(size_t)tid * n + i] = d;
        }
    }
}

// ---------------------------------------------------------------------------
// LSTM shared pieces. Lane layout per wave: quad u = lane>>2 (unit slot:
// d=u/5, unit=u%5, concat order [dir0,dir1]); gt=lane&3 in {i,f,g,o}.
// Weights pre-scaled by -log2e (sig) / -2log2e (tanh); c carried pre-scaled.
// ---------------------------------------------------------------------------
struct SB { float v[GCNW]; };

__device__ __forceinline__ SB bc(float x) {
    SB r;
    #pragma unroll
    for (int j = 0; j < GCNW; ++j) r.v[j] = rl(x, 4 * j);
    return r;
}

__device__ __forceinline__ SB loadrow(const float* __restrict__ p) {
    SB r;
    #pragma unroll
    for (int j = 0; j < GCNW; ++j) r.v[j] = p[j];
    return r;
}

__device__ __forceinline__ SB ldsrow(const float* p) {
    SB r;
    float4 a = ((const float4*)p)[0];
    float4 b = ((const float4*)p)[1];
    float2 c = *(const float2*)(p + 8);
    r.v[0]=a.x; r.v[1]=a.y; r.v[2]=a.z; r.v[3]=a.w;
    r.v[4]=b.x; r.v[5]=b.y; r.v[6]=b.z; r.v[7]=b.w;
    r.v[8]=c.x; r.v[9]=c.y;
    return r;
}

// 10-term dot, 4 accumulators (depth 3 + 2 merges), seeded with init
__device__ __forceinline__ float dot10(const float (&w)[GCNW], const SB& x, float init) {
    float a0 = fmaf(w[0], x.v[0], init);
    float a1 = w[1] * x.v[1];
    float a2 = w[2] * x.v[2];
    float a3 = w[3] * x.v[3];
    a0 = fmaf(w[4], x.v[4], a0);
    a1 = fmaf(w[5], x.v[5], a1);
    a2 = fmaf(w[6], x.v[6], a2);
    a3 = fmaf(w[7], x.v[7], a3);
    a0 = fmaf(w[8], x.v[8], a0);
    a1 = fmaf(w[9], x.v[9], a1);
    return (a0 + a1) + (a2 + a3);
}

// activation + cell update from pre-scaled preactivation
__device__ __forceinline__ float act2(float acc, float& cS, float P, float Qn) {
    float e  = fexp2(acc);
    float r  = frcp(1.f + e);
    float tg = fmaf(Qn, e, P);
    float av = tg * r;                       // sig(a) or -2log2e*tanh(a)
    float fv = qb<1>(av), gv = qb<2>(av), ov = qb<3>(av);
    float cn = fmaf(fv, cS, av * gv);        // scaled c', valid on gt==0
    cS = cn;
    float e2 = fexp2(cn);
    float r2 = frcp(1.f + e2);
    return fmaf(-ov, e2, ov) * r2;           // hn = ov*tanh(c_true)
}

// ---- k_enc: 3 waves, wave w = layer w; chunk pipeline through LDS ---------
__global__ __launch_bounds__(192, 1) void k_enc(
    const float* __restrict__ Hr,    // (n,10) encode inputs, row-major
    const float* __restrict__ W_ih, const float* __restrict__ W_hh,
    const float* __restrict__ b_ih, const float* __restrict__ b_hh,
    const float* __restrict__ h0,   const float* __restrict__ c0,
    float* __restrict__ hand,        // out: [w*20+u]=h_last, [w*20+10+u]=cS_last
    int n)
{
    __shared__ __align__(16) float buf0[2][CHK * CROW];  // layer0 -> layer1
    __shared__ __align__(16) float buf1[2][CHK * CROW];  // layer1 -> layer2

    const int  lane = threadIdx.x & 63;
    const int  wid  = threadIdx.x >> 6;        // 0..2 = layer
    const int  ul   = lane >> 2, gt = lane & 3;
    const bool actl = ul < GCNW;
    const bool wl10 = actl && (gt == 0);
    const int  ulc  = actl ? ul : 0;
    const int  dd   = ulc / 5, un = ulc % 5;
    const int  row  = gt * 5 + un;
    const bool isg  = (gt == 2);
    const float c2e = isg ? (-2.f * LOG2E) : (-LOG2E);
    const float P   = isg ? (-2.f * LOG2E) : 1.f;
    const float Qn  = isg ? ( 2.f * LOG2E) : 0.f;

    float wih[GCNW], whh[GCNW], bias, cS;
    {
        const int k = 2 * wid + dd;
        #pragma unroll
        for (int j = 0; j < GCNW; ++j)
            wih[j] = actl ? c2e * W_ih[(k * 20 + row) * 10 + j] : 0.f;
        #pragma unroll
        for (int j = 0; j < GCNW; ++j)
            whh[j] = (actl && (j / 5) == dd) ? c2e * W_hh[(k * 20 + row) * 5 + (j % 5)] : 0.f;
        bias = actl ? c2e * (b_ih[k * 20 + row] + b_hh[k * 20 + row]) : 0.f;
        cS   = actl ? (-2.f * LOG2E) * c0[k * 5 + un] : 0.f;
    }
    SB B = bc(actl ? h0[(2 * wid + dd) * 5 + un] : 0.f);
    float hl = 0.f;

    const int NCH = n / CHK;
    #pragma unroll 1
    for (int p = 0; p < NCH + 2; ++p) {
        const int ck = p - wid;
        if (ck >= 0 && ck < NCH) {
            if (wid == 0) {
                const float* xrow = Hr + (size_t)ck * CHK * GCNW;
                float* wb = buf0[ck & 1];
                float xd = dot10(wih, loadrow(xrow), bias);
                #pragma unroll 1
                for (int tt = 0; tt < CHK; ++tt) {
                    const int tp = (tt + 1 < CHK) ? tt + 1 : tt;
                    float xdn = dot10(wih, loadrow(xrow + tp * GCNW), bias);  // off-chain
                    float nh  = act2(dot10(whh, B, xd), cS, P, Qn);
                    B = bc(nh); hl = nh;
                    if (wl10) wb[tt * CROW + ul] = nh;
                    xd = xdn;
                }
            } else if (wid == 1) {
                const float* rb = buf0[ck & 1];
                float*       wb = buf1[ck & 1];
                float xd = dot10(wih, ldsrow(rb), bias);
                #pragma unroll 1
                for (int tt = 0; tt < CHK; ++tt) {
                    const int tp = (tt + 1 < CHK) ? tt + 1 : tt;
                    float xdn = dot10(wih, ldsrow(rb + tp * CROW), bias);     // off-chain
                    float nh  = act2(dot10(whh, B, xd), cS, P, Qn);
                    B = bc(nh); hl = nh;
                    if (wl10) wb[tt * CROW + ul] = nh;
                    xd = xdn;
                }
            } else {
                const float* rb = buf1[ck & 1];
                float xd = dot10(wih, ldsrow(rb), bias);
                #pragma unroll 1
                for (int tt = 0; tt < CHK; ++tt) {
                    const int tp = (tt + 1 < CHK) ? tt + 1 : tt;
                    float xdn = dot10(wih, ldsrow(rb + tp * CROW), bias);     // off-chain
                    float nh  = act2(dot10(whh, B, xd), cS, P, Qn);
                    B = bc(nh); hl = nh;
                    xd = xdn;
                }
            }
        }
        __syncthreads();
    }
    if (wl10) { hand[wid * 20 + ul] = hl; hand[wid * 20 + 10 + ul] = cS; }
}

// ---- k_dec: 1 wave, autoregressive; hp (bias + Whh.h) carried off-chain ---
__global__ __launch_bounds__(64, 1) void k_dec(
    const float* __restrict__ W_ih, const float* __restrict__ W_hh,
    const float* __restrict__ b_ih, const float* __restrict__ b_hh,
    const float* __restrict__ hand,  // from k_enc
    const float* __restrict__ tok,
    const float* __restrict__ Wo,   const float* __restrict__ bo,
    float* __restrict__ out, int n)
{
    const int  lane = threadIdx.x;
    const int  ul   = lane >> 2, gt = lane & 3;
    const bool actl = ul < GCNW;
    const int  ulc  = actl ? ul : 0;
    const int  dd   = ulc / 5, un = ulc % 5;
    const int  row  = gt * 5 + un;
    const bool isg  = (gt == 2);
    const float c2e = isg ? (-2.f * LOG2E) : (-LOG2E);
    const float P   = isg ? (-2.f * LOG2E) : 1.f;
    const float Qn  = isg ? ( 2.f * LOG2E) : 0.f;

    float wih[3][GCNW], whh[3][GCNW], bias[3], cS[3];
    #pragma unroll
    for (int l = 0; l < 3; ++l) {
        const int k = 2 * l + dd;
        #pragma unroll
        for (int j = 0; j < GCNW; ++j)
            wih[l][j] = actl ? c2e * W_ih[(k * 20 + row) * 10 + j] : 0.f;
        #pragma unroll
        for (int j = 0; j < GCNW; ++j)
            whh[l][j] = (actl && (j / 5) == dd) ? c2e * W_hh[(k * 20 + row) * 5 + (j % 5)] : 0.f;
        bias[l] = actl ? c2e * (b_ih[k * 20 + row] + b_hh[k * 20 + row]) : 0.f;
        cS[l]   = actl ? hand[l * 20 + 10 + ulc] : 0.f;
    }
    SB B0 = bc(actl ? hand[0 * 20 + ulc] : 0.f);
    SB B1 = bc(actl ? hand[1 * 20 + ulc] : 0.f);
    SB B2 = bc(actl ? hand[2 * 20 + ulc] : 0.f);

    float wo[GCNW];
    #pragma unroll
    for (int j = 0; j < GCNW; ++j) wo[j] = -LOG2E * Wo[j];
    const float bos = -LOG2E * bo[0];
    SB X = loadrow(tok);

    // hp pipeline: hp_l = bias_l + Whh_l . h_l  (off the serial chain)
    float hp0 = dot10(whh[0], B0, bias[0]);
    float hp1 = dot10(whh[1], B1, bias[1]);
    float hp2 = dot10(whh[2], B2, bias[2]);

    #pragma unroll 1
    for (int t64 = 0; t64 < n / 64; ++t64) {
        float ob = 0.f;
        #pragma unroll 1
        for (int tt = 0; tt < 64; ++tt) {
            float n0 = act2(dot10(wih[0], X, hp0), cS[0], P, Qn);
            B0 = bc(n0);
            hp0 = dot10(whh[0], B0, bias[0]);                 // off-chain
            float n1 = act2(dot10(wih[1], B0, hp1), cS[1], P, Qn);
            B1 = bc(n1);
            hp1 = dot10(whh[1], B1, bias[1]);                 // off-chain
            float n2 = act2(dot10(wih[2], B1, hp2), cS[2], P, Qn);
            B2 = bc(n2);
            hp2 = dot10(whh[2], B2, bias[2]);                 // off-chain
            X = B2;
            float d0 = bos, d1 = 0.f;
            #pragma unroll
            for (int j = 0; j < GCNW; j += 2) {
                d0 = fmaf(wo[j],     B2.v[j],     d0);
                d1 = fmaf(wo[j + 1], B2.v[j + 1], d1);
            }
            float val = frcp(1.f + fexp2(d0 + d1));
            ob = (lane == tt) ? val : ob;
        }
        out[t64 * 64 + lane] = ob;
    }
}

extern "C" void kernel_launch(void* const* d_in, const int* in_sizes, int n_in,
                              void* d_out, int out_size, void* d_ws, size_t ws_size,
                              hipStream_t stream) {
    const float* A    = (const float*)d_in[0];
    const float* X    = (const float*)d_in[1];
    const float* W0   = (const float*)d_in[2];
    const float* W1   = (const float*)d_in[3];
    const float* W2   = (const float*)d_in[4];
    const float* W_ih = (const float*)d_in[5];
    const float* W_hh = (const float*)d_in[6];
    const float* b_ih = (const float*)d_in[7];
    const float* b_hh = (const float*)d_in[8];
    const float* h0   = (const float*)d_in[9];
    const float* c0   = (const float*)d_in[10];
    const float* tok  = (const float*)d_in[11];
    const float* Wo   = (const float*)d_in[12];
    const float* bo   = (const float*)d_in[13];
    float* out = (float*)d_out;

    const int n    = out_size;            // 4096
    const int feat = in_sizes[1] / n;     // 1024

    // workspace: s (n) | P0 (10n) | P1 (10n) | hand (64)
    float* s    = (float*)d_ws;
    float* P0   = s + n;
    float* P1   = P0 + (size_t)n * GCNW;
    float* hand = P1 + (size_t)n * GCNW;

    k_pre<<<2 * n, 256, 0, stream>>>(A, X, W0, s, P0, n, feat);        // s, Y0t
    k_ap <<<n,     256, 0, stream>>>(A, s, P0, W1,      P1, n, 0);     // Y1t (10,n)
    k_ap <<<n,     256, 0, stream>>>(A, s, P1, W2,      P0, n, 0);     // Y2t (10,n)
    k_ap <<<n,     256, 0, stream>>>(A, s, P0, nullptr, P1, n, 1);     // H  (n,10)
    k_enc<<<1, 192, 0, stream>>>(P1, W_ih, W_hh, b_ih, b_hh, h0, c0, hand, n);
    k_dec<<<1, 64, 0, stream>>>(W_ih, W_hh, b_ih, b_hh, hand, tok, Wo, bo, out, n);
}

// Round 6
// 2268.810 us; speedup vs baseline: 2.2012x; 1.2073x over previous
//
#include <hip/hip_runtime.h>
#include <math.h>

// ---------------------------------------------------------------------------
// GraphConvNetLSTM: GCN (3 layers, reassociated Ahat@(H@W.T)) + 3-layer bidir
// LSTM. k_enc: 3 waves (one per layer) pipelined over 32-step chunks via
// double-buffered LDS; H-chunks bulk-prefetched into LDS by wave 0 (no
// global load on any serial chain). k_dec: 1 wave, autoregressive, h-side
// dots carried off-chain. Chain per stage = dot(depth 5) + activation only.
// ---------------------------------------------------------------------------

#define GCNW 10
#define LOG2E 1.4426950408889634f
#define CHK  32      // pipeline chunk (timesteps)
#define CROW 12      // padded LDS row stride (floats), 48B keeps 16B align

__device__ __forceinline__ float rl(float v, int l) {
    return __int_as_float(__builtin_amdgcn_readlane(__float_as_int(v), l));
}
__device__ __forceinline__ float frcp(float x) { return __builtin_amdgcn_rcpf(x); }

#if __has_builtin(__builtin_amdgcn_exp2f)
__device__ __forceinline__ float fexp2(float x) { return __builtin_amdgcn_exp2f(x); }
#else
__device__ __forceinline__ float fexp2(float x) { return __expf(x * 0.6931471805599453f); }
#endif

template <int L>
__device__ __forceinline__ float qb(float v) {
    constexpr int ctrl = L | (L << 2) | (L << 4) | (L << 6);
    int r = __builtin_amdgcn_update_dpp(0, __float_as_int(v), ctrl, 0xF, 0xF, true);
    return __int_as_float(r);
}

__device__ __forceinline__ float selu_f(float x) {
    const float lam = 1.0507009873554805f;
    const float la  = 1.7580993408473766f;
    return x > 0.f ? lam * x : la * (__expf(x) - 1.f);
}

// ---- k_pre: blocks [0,n) rowsum->s ; blocks [n,2n) Y0t[o][i] = X[i]@W0.T ---
__global__ __launch_bounds__(256) void k_pre(const float* __restrict__ A,
                                             const float* __restrict__ X,
                                             const float* __restrict__ W0,
                                             float* __restrict__ s,
                                             float* __restrict__ Y0t,
                                             int n, int feat) {
    const int b   = blockIdx.x;
    const int tid = threadIdx.x;
    if (b < n) {
        __shared__ float red[256];
        const float4* row4 = (const float4*)(A + (size_t)b * n);
        float acc = 0.f;
        for (int j = tid; j < n / 4; j += 256) {
            float4 a = row4[j];
            acc += (a.x + a.y) + (a.z + a.w);
        }
        red[tid] = acc; __syncthreads();
        #pragma unroll
        for (int w = 128; w > 0; w >>= 1) {
            if (tid < w) red[tid] += red[tid + w];
            __syncthreads();
        }
        if (tid == 0) {
            float deg = red[0];
            s[b] = (deg > 0.f) ? rsqrtf(deg) : 0.f;
        }
    } else {
        const int i = b - n;
        float acc[GCNW];
        #pragma unroll
        for (int o = 0; o < GCNW; ++o) acc[o] = 0.f;
        const float* xr = X + (size_t)i * feat;
        for (int j = tid; j < feat; j += 256) {
            float xv = xr[j];
            #pragma unroll
            for (int o = 0; o < GCNW; ++o) acc[o] = fmaf(xv, W0[o * feat + j], acc[o]);
        }
        #pragma unroll
        for (int o = 0; o < GCNW; ++o) {
            float v = acc[o];
            #pragma unroll
            for (int off = 32; off > 0; off >>= 1) v += __shfl_xor(v, off);
            acc[o] = v;
        }
        __shared__ float part[4][GCNW];
        const int wv = tid >> 6, ln = tid & 63;
        if (ln == 0) {
            #pragma unroll
            for (int o = 0; o < GCNW; ++o) part[wv][o] = acc[o];
        }
        __syncthreads();
        if (tid < GCNW)
            Y0t[(size_t)tid * n + i] =
                part[0][tid] + part[1][tid] + part[2][tid] + part[3][tid];
    }
}

// ---- k_ap: z = selu(s_i*(sum_j A_ij s_j Y_j + s_i Y_i)); if W: fuse next
//      layer matvec, write (10,n); else write z (rowmajor -> (n,10)). -------
__global__ __launch_bounds__(256) void k_ap(const float* __restrict__ A,
                                            const float* __restrict__ s,
                                            const float* __restrict__ Yt,
                                            const float* __restrict__ W,
                                            float* __restrict__ Ot, int n,
                                            int rowmajor) {
    const int i   = blockIdx.x;
    const int tid = threadIdx.x;
    float acc[GCNW];
    #pragma unroll
    for (int o = 0; o < GCNW; ++o) acc[o] = 0.f;
    const float4* a4 = (const float4*)(A + (size_t)i * n);
    const float4* s4 = (const float4*)s;
    for (int j4 = tid; j4 < n / 4; j4 += 256) {
        float4 a  = a4[j4];
        float4 sv = s4[j4];
        a.x *= sv.x; a.y *= sv.y; a.z *= sv.z; a.w *= sv.w;
        #pragma unroll
        for (int o = 0; o < GCNW; ++o) {
            float4 y = ((const float4*)(Yt + (size_t)o * n))[j4];
            acc[o] = fmaf(a.x, y.x, acc[o]);
            acc[o] = fmaf(a.y, y.y, acc[o]);
            acc[o] = fmaf(a.z, y.z, acc[o]);
            acc[o] = fmaf(a.w, y.w, acc[o]);
        }
    }
    #pragma unroll
    for (int o = 0; o < GCNW; ++o) {
        float v = acc[o];
        #pragma unroll
        for (int off = 32; off > 0; off >>= 1) v += __shfl_xor(v, off);
        acc[o] = v;
    }
    __shared__ float part[4][GCNW];
    __shared__ float zsh[GCNW];
    const int wv = tid >> 6, ln = tid & 63;
    if (ln == 0) {
        #pragma unroll
        for (int o = 0; o < GCNW; ++o) part[wv][o] = acc[o];
    }
    __syncthreads();
    if (tid < GCNW) {
        float dot = part[0][tid] + part[1][tid] + part[2][tid] + part[3][tid];
        float si  = s[i];
        float z   = selu_f(si * (dot + si * Yt[(size_t)tid * n + i]));
        if (W) zsh[tid] = z;
        else if (rowmajor) Ot[(size_t)i * GCNW + tid] = z;
        else               Ot[(size_t)tid * n + i]    = z;
    }
    if (W) {
        __syncthreads();
        if (tid < GCNW) {
            float d = 0.f;
            #pragma unroll
            for (int u = 0; u < GCNW; ++u) d = fmaf(zsh[u], W[tid * GCNW + u], d);
            Ot[(size_t)tid * n + i] = d;
        }
    }
}

// ---------------------------------------------------------------------------
// LSTM shared pieces. Lane layout per wave: quad u = lane>>2 (unit slot:
// d=u/5, unit=u%5, concat order [dir0,dir1]); gt=lane&3 in {i,f,g,o}.
// Weights pre-scaled by -log2e (sig) / -2log2e (tanh); c carried pre-scaled.
// ---------------------------------------------------------------------------
struct SB { float v[GCNW]; };

__device__ __forceinline__ SB bc(float x) {
    SB r;
    #pragma unroll
    for (int j = 0; j < GCNW; ++j) r.v[j] = rl(x, 4 * j);
    return r;
}

__device__ __forceinline__ SB loadrow(const float* __restrict__ p) {
    SB r;
    #pragma unroll
    for (int j = 0; j < GCNW; ++j) r.v[j] = p[j];
    return r;
}

__device__ __forceinline__ SB ldsrow(const float* p) {
    SB r;
    float4 a = ((const float4*)p)[0];
    float4 b = ((const float4*)p)[1];
    float2 c = *(const float2*)(p + 8);
    r.v[0]=a.x; r.v[1]=a.y; r.v[2]=a.z; r.v[3]=a.w;
    r.v[4]=b.x; r.v[5]=b.y; r.v[6]=b.z; r.v[7]=b.w;
    r.v[8]=c.x; r.v[9]=c.y;
    return r;
}

// 10-term dot, 4 accumulators (depth 3 + 2 merges), seeded with init
__device__ __forceinline__ float dot10(const float (&w)[GCNW], const SB& x, float init) {
    float a0 = fmaf(w[0], x.v[0], init);
    float a1 = w[1] * x.v[1];
    float a2 = w[2] * x.v[2];
    float a3 = w[3] * x.v[3];
    a0 = fmaf(w[4], x.v[4], a0);
    a1 = fmaf(w[5], x.v[5], a1);
    a2 = fmaf(w[6], x.v[6], a2);
    a3 = fmaf(w[7], x.v[7], a3);
    a0 = fmaf(w[8], x.v[8], a0);
    a1 = fmaf(w[9], x.v[9], a1);
    return (a0 + a1) + (a2 + a3);
}

// activation + cell update from pre-scaled preactivation
__device__ __forceinline__ float act2(float acc, float& cS, float P, float Qn) {
    float e  = fexp2(acc);
    float r  = frcp(1.f + e);
    float tg = fmaf(Qn, e, P);
    float av = tg * r;                       // sig(a) or -2log2e*tanh(a)
    float fv = qb<1>(av), gv = qb<2>(av), ov = qb<3>(av);
    float cn = fmaf(fv, cS, av * gv);        // scaled c', valid on gt==0
    cS = cn;
    float e2 = fexp2(cn);
    float r2 = frcp(1.f + e2);
    return fmaf(-ov, e2, ov) * r2;           // hn = ov*tanh(c_true)
}

// ---- k_enc: 3 waves = 3 layers; all stage inputs come from LDS; wave 0
//      bulk-prefetches H chunks into a double-buffered LDS input buffer. ----
__global__ __launch_bounds__(192, 1) void k_enc(
    const float* __restrict__ Hr,    // (n,10) encode inputs, row-major
    const float* __restrict__ W_ih, const float* __restrict__ W_hh,
    const float* __restrict__ b_ih, const float* __restrict__ b_hh,
    const float* __restrict__ h0,   const float* __restrict__ c0,
    float* __restrict__ hand,        // out: [w*20+u]=h_last, [w*20+10+u]=cS_last
    int n)
{
    __shared__ __align__(16) float bufI[2][CHK * CROW];  // H input (wave 0)
    __shared__ __align__(16) float buf0[2][CHK * CROW];  // layer0 -> layer1
    __shared__ __align__(16) float buf1[2][CHK * CROW];  // layer1 -> layer2

    const int  lane = threadIdx.x & 63;
    const int  wid  = threadIdx.x >> 6;        // 0..2 = layer
    const int  ul   = lane >> 2, gt = lane & 3;
    const bool actl = ul < GCNW;
    const bool wl10 = actl && (gt == 0);
    const int  ulc  = actl ? ul : 0;
    const int  dd   = ulc / 5, un = ulc % 5;
    const int  row  = gt * 5 + un;
    const bool isg  = (gt == 2);
    const float c2e = isg ? (-2.f * LOG2E) : (-LOG2E);
    const float P   = isg ? (-2.f * LOG2E) : 1.f;
    const float Qn  = isg ? ( 2.f * LOG2E) : 0.f;

    float wih[GCNW], whh[GCNW], bias, cS;
    {
        const int k = 2 * wid + dd;
        #pragma unroll
        for (int j = 0; j < GCNW; ++j)
            wih[j] = actl ? c2e * W_ih[(k * 20 + row) * 10 + j] : 0.f;
        #pragma unroll
        for (int j = 0; j < GCNW; ++j)
            whh[j] = (actl && (j / 5) == dd) ? c2e * W_hh[(k * 20 + row) * 5 + (j % 5)] : 0.f;
        bias = actl ? c2e * (b_ih[k * 20 + row] + b_hh[k * 20 + row]) : 0.f;
        cS   = actl ? (-2.f * LOG2E) * c0[k * 5 + un] : 0.f;
    }
    SB B = bc(actl ? h0[(2 * wid + dd) * 5 + un] : 0.f);
    float hl = 0.f;

    // per-lane element indices for the bulk H copy: 5 elems/lane (320 total)
    const int e0 = lane * 5;
    int crow[5], ccol[5];
    #pragma unroll
    for (int q = 0; q < 5; ++q) { crow[q] = (e0 + q) / GCNW; ccol[q] = (e0 + q) % GCNW; }

    // prologue: wave 0 stages chunk 0
    if (wid == 0) {
        const float* src = Hr;
        #pragma unroll
        for (int q = 0; q < 5; ++q)
            bufI[0][crow[q] * CROW + ccol[q]] = src[e0 + q];
    }
    __syncthreads();

    const int NCH = n / CHK;
    #pragma unroll 1
    for (int p = 0; p < NCH + 2; ++p) {
        const int ck = p - wid;
        if (wid == 0) {
            // issue next chunk's global loads up front (land during compute)
            float tmp[5];
            const bool pf = (p + 1 < NCH) && (p < NCH);
            if (pf) {
                const float* src = Hr + (size_t)(p + 1) * CHK * GCNW;
                #pragma unroll
                for (int q = 0; q < 5; ++q) tmp[q] = src[e0 + q];
            }
            if (ck < NCH) {
                const float* rb = bufI[ck & 1];
                float*       wb = buf0[ck & 1];
                float xd = dot10(wih, ldsrow(rb), bias);
                #pragma unroll 1
                for (int tt = 0; tt < CHK; ++tt) {
                    const int tp = (tt + 1 < CHK) ? tt + 1 : tt;
                    float xdn = dot10(wih, ldsrow(rb + tp * CROW), bias);   // off-chain
                    float nh  = act2(dot10(whh, B, xd), cS, P, Qn);
                    B = bc(nh);
                    if (wl10) wb[tt * CROW + ul] = nh;
                    xd = xdn;
                }
            }
            if (pf) {
                float* db = bufI[(p + 1) & 1];
                #pragma unroll
                for (int q = 0; q < 5; ++q) db[crow[q] * CROW + ccol[q]] = tmp[q];
            }
        } else if (ck >= 0 && ck < NCH) {
            if (wid == 1) {
                const float* rb = buf0[ck & 1];
                float*       wb = buf1[ck & 1];
                float xd = dot10(wih, ldsrow(rb), bias);
                #pragma unroll 1
                for (int tt = 0; tt < CHK; ++tt) {
                    const int tp = (tt + 1 < CHK) ? tt + 1 : tt;
                    float xdn = dot10(wih, ldsrow(rb + tp * CROW), bias);   // off-chain
                    float nh  = act2(dot10(whh, B, xd), cS, P, Qn);
                    B = bc(nh); hl = nh;
                    if (wl10) wb[tt * CROW + ul] = nh;
                    xd = xdn;
                }
            } else {
                const float* rb = buf1[ck & 1];
                float xd = dot10(wih, ldsrow(rb), bias);
                #pragma unroll 1
                for (int tt = 0; tt < CHK; ++tt) {
                    const int tp = (tt + 1 < CHK) ? tt + 1 : tt;
                    float xdn = dot10(wih, ldsrow(rb + tp * CROW), bias);   // off-chain
                    float nh  = act2(dot10(whh, B, xd), cS, P, Qn);
                    B = bc(nh); hl = nh;
                    xd = xdn;
                }
            }
        }
        __syncthreads();
    }
    if (wl10) { hand[wid * 20 + ul] = hl; hand[wid * 20 + 10 + ul] = cS; }
}

// ---- k_dec: 1 wave, autoregressive; hp (bias + Whh.h) carried off-chain ---
__global__ __launch_bounds__(64, 1) void k_dec(
    const float* __restrict__ W_ih, const float* __restrict__ W_hh,
    const float* __restrict__ b_ih, const float* __restrict__ b_hh,
    const float* __restrict__ hand,  // from k_enc
    const float* __restrict__ tok,
    const float* __restrict__ Wo,   const float* __restrict__ bo,
    float* __restrict__ out, int n)
{
    const int  lane = threadIdx.x;
    const int  ul   = lane >> 2, gt = lane & 3;
    const bool actl = ul < GCNW;
    const int  ulc  = actl ? ul : 0;
    const int  dd   = ulc / 5, un = ulc % 5;
    const int  row  = gt * 5 + un;
    const bool isg  = (gt == 2);
    const float c2e = isg ? (-2.f * LOG2E) : (-LOG2E);
    const float P   = isg ? (-2.f * LOG2E) : 1.f;
    const float Qn  = isg ? ( 2.f * LOG2E) : 0.f;

    float wih[3][GCNW], whh[3][GCNW], bias[3], cS[3];
    #pragma unroll
    for (int l = 0; l < 3; ++l) {
        const int k = 2 * l + dd;
        #pragma unroll
        for (int j = 0; j < GCNW; ++j)
            wih[l][j] = actl ? c2e * W_ih[(k * 20 + row) * 10 + j] : 0.f;
        #pragma unroll
        for (int j = 0; j < GCNW; ++j)
            whh[l][j] = (actl && (j / 5) == dd) ? c2e * W_hh[(k * 20 + row) * 5 + (j % 5)] : 0.f;
        bias[l] = actl ? c2e * (b_ih[k * 20 + row] + b_hh[k * 20 + row]) : 0.f;
        cS[l]   = actl ? hand[l * 20 + 10 + ulc] : 0.f;
    }
    SB B0 = bc(actl ? hand[0 * 20 + ulc] : 0.f);
    SB B1 = bc(actl ? hand[1 * 20 + ulc] : 0.f);
    SB B2 = bc(actl ? hand[2 * 20 + ulc] : 0.f);

    float wo[GCNW];
    #pragma unroll
    for (int j = 0; j < GCNW; ++j) wo[j] = -LOG2E * Wo[j];
    const float bos = -LOG2E * bo[0];
    SB X = loadrow(tok);

    // hp pipeline: hp_l = bias_l + Whh_l . h_l  (off the serial chain)
    float hp0 = dot10(whh[0], B0, bias[0]);
    float hp1 = dot10(whh[1], B1, bias[1]);
    float hp2 = dot10(whh[2], B2, bias[2]);

    #pragma unroll 1
    for (int t64 = 0; t64 < n / 64; ++t64) {
        float ob = 0.f;
        #pragma unroll 1
        for (int tt = 0; tt < 64; ++tt) {
            float n0 = act2(dot10(wih[0], X, hp0), cS[0], P, Qn);
            B0 = bc(n0);
            hp0 = dot10(whh[0], B0, bias[0]);                 // off-chain
            float n1 = act2(dot10(wih[1], B0, hp1), cS[1], P, Qn);
            B1 = bc(n1);
            hp1 = dot10(whh[1], B1, bias[1]);                 // off-chain
            float n2 = act2(dot10(wih[2], B1, hp2), cS[2], P, Qn);
            B2 = bc(n2);
            hp2 = dot10(whh[2], B2, bias[2]);                 // off-chain
            X = B2;
            float d0 = bos, d1 = 0.f;
            #pragma unroll
            for (int j = 0; j < GCNW; j += 2) {
                d0 = fmaf(wo[j],     B2.v[j],     d0);
                d1 = fmaf(wo[j + 1], B2.v[j + 1], d1);
            }
            float val = frcp(1.f + fexp2(d0 + d1));
            ob = (lane == tt) ? val : ob;
        }
        out[t64 * 64 + lane] = ob;
    }
}

extern "C" void kernel_launch(void* const* d_in, const int* in_sizes, int n_in,
                              void* d_out, int out_size, void* d_ws, size_t ws_size,
                              hipStream_t stream) {
    const float* A    = (const float*)d_in[0];
    const float* X    = (const float*)d_in[1];
    const float* W0   = (const float*)d_in[2];
    const float* W1   = (const float*)d_in[3];
    const float* W2   = (const float*)d_in[4];
    const float* W_ih = (const float*)d_in[5];
    const float* W_hh = (const float*)d_in[6];
    const float* b_ih = (const float*)d_in[7];
    const float* b_hh = (const float*)d_in[8];
    const float* h0   = (const float*)d_in[9];
    const float* c0   = (const float*)d_in[10];
    const float* tok  = (const float*)d_in[11];
    const float* Wo   = (const float*)d_in[12];
    const float* bo   = (const float*)d_in[13];
    float* out = (float*)d_out;

    const int n    = out_size;            // 4096
    const int feat = in_sizes[1] / n;     // 1024

    // workspace: s (n) | P0 (10n) | P1 (10n) | hand (64)
    float* s    = (float*)d_ws;
    float* P0   = s + n;
    float* P1   = P0 + (size_t)n * GCNW;
    float* hand = P1 + (size_t)n * GCNW;

    k_pre<<<2 * n, 256, 0, stream>>>(A, X, W0, s, P0, n, feat);        // s, Y0t
    k_ap <<<n,     256, 0, stream>>>(A, s, P0, W1,      P1, n, 0);     // Y1t (10,n)
    k_ap <<<n,     256, 0, stream>>>(A, s, P1, W2,      P0, n, 0);     // Y2t (10,n)
    k_ap <<<n,     256, 0, stream>>>(A, s, P0, nullptr, P1, n, 1);     // H  (n,10)
    k_enc<<<1, 192, 0, stream>>>(P1, W_ih, W_hh, b_ih, b_hh, h0, c0, hand, n);
    k_dec<<<1, 64, 0, stream>>>(W_ih, W_hh, b_ih, b_hh, hand, tok, Wo, bo, out, n);
}